// Round 6
// baseline (277.003 us; speedup 1.0000x reference)
//
#include <hip/hip_runtime.h>

typedef unsigned short ushort_t;
typedef unsigned int uint_t;
typedef unsigned long long u64;
typedef __attribute__((ext_vector_type(8))) short bf16x8;
typedef __attribute__((ext_vector_type(4))) float f32x4;
typedef __attribute__((ext_vector_type(16))) float f32x16;
typedef __attribute__((ext_vector_type(4))) uint_t u32x4;

#define B_ 8
#define L_ 1024
#define C_ 768
#define H_ 6
#define D_ 128
#define BH_ 48
#define NEGINF (-1e9f)
#define THR_ 8.0f

#define AS1 __attribute__((address_space(1)))
#define AS3 __attribute__((address_space(3)))

// round-to-nearest-even f32 -> bf16
__device__ __forceinline__ ushort_t f2bf(float f) {
  uint_t u = __builtin_bit_cast(uint_t, f);
  u += 0x7fffu + ((u >> 16) & 1u);
  return (ushort_t)(u >> 16);
}

// ---------------------------------------------------------------- converts
__global__ void cvt_f32_bf16(const float* __restrict__ in, ushort_t* __restrict__ out, int n8) {
  int i = blockIdx.x * 256 + threadIdx.x;
  if (i >= n8) return;
  const float4* p = (const float4*)in + (size_t)i * 2;
  float4 a = p[0], b = p[1];
  uint4 r;
  r.x = (uint_t)f2bf(a.x) | ((uint_t)f2bf(a.y) << 16);
  r.y = (uint_t)f2bf(a.z) | ((uint_t)f2bf(a.w) << 16);
  r.z = (uint_t)f2bf(b.x) | ((uint_t)f2bf(b.y) << 16);
  r.w = (uint_t)f2bf(b.z) | ((uint_t)f2bf(b.w) << 16);
  ((uint4*)out)[i] = r;
}

// ------------------------------------------------- bit-pack a1 / d<=2 / d<=3
__global__ __launch_bounds__(256)
void pack_masks(const int* __restrict__ adj, const int* __restrict__ dist,
                u64* __restrict__ a1p, u64* __restrict__ d2p, u64* __restrict__ d3p) {
  int l = blockIdx.x, b = blockIdx.y, t = threadIdx.x;
  size_t base = ((size_t)b * L_ + l) * L_;
  size_t rb = ((size_t)b * L_ + l) * 16;
  #pragma unroll
  for (int it = 0; it < 4; ++it) {
    int c = it * 256 + t;
    int av = adj[base + c];
    int dv = dist[base + c];
    u64 m1 = __ballot((av > 0) || (c == l));
    u64 m2 = __ballot(dv <= 2);
    u64 m3 = __ballot(dv <= 3);
    if ((t & 63) == 0) {
      int w = it * 4 + (t >> 6);
      a1p[rb + w] = m1; d2p[rb + w] = m2; d3p[rb + w] = m3;
    }
  }
}

// ------------------------------------------------- 2-hop closure (bit OR)
__global__ __launch_bounds__(64)
void hop2(const u64* __restrict__ a1p, u64* __restrict__ a2p) {
  int tid = blockIdx.x * 64 + threadIdx.x;   // 0..8191 = (b,l)
  int b = tid >> 10;
  size_t rb = (size_t)tid * 16;
  u64 row[16], acc[16];
  #pragma unroll
  for (int j = 0; j < 16; ++j) { row[j] = a1p[rb + j]; acc[j] = 0ULL; }
  bool done = false;
  #pragma unroll
  for (int mw = 0; mw < 16; ++mw) {
    if (done) continue;
    u64 bits = row[mw];
    while (bits) {
      int tz = __builtin_ctzll(bits); bits &= bits - 1;
      const u64* src = a1p + (((size_t)b << 10) + (mw << 6) + tz) * 16;
      u64 band = ~0ULL;
      #pragma unroll
      for (int j = 0; j < 16; ++j) { acc[j] |= src[j]; band &= acc[j]; }
      if (band == ~0ULL) { done = true; break; }
    }
  }
  #pragma unroll
  for (int j = 0; j < 16; ++j) a2p[rb + j] = acc[j];
}

// ------------------------------------------------- bf16 GEMM  C = A @ B^T
template<int EPI>
__global__ __launch_bounds__(256)
void gemm_bt(const ushort_t* __restrict__ A, const ushort_t* __restrict__ Bm,
             int N, int K,
             ushort_t* __restrict__ qo, ushort_t* __restrict__ ko,
             ushort_t* __restrict__ vTo, ushort_t* __restrict__ vo,
             float* __restrict__ fo) {
  __shared__ __align__(16) ushort_t As[128 * 32];
  __shared__ __align__(16) ushort_t Bs[128 * 32];
  int t = threadIdx.x;
  int lane = t & 63, lo = lane & 15, hi = lane >> 4;
  int wv = t >> 6, wm = wv >> 1, wn = wv & 1;
  int m0 = blockIdx.y * 128, n0 = blockIdx.x * 128;

  f32x4 acc[4][4];
  #pragma unroll
  for (int mi = 0; mi < 4; ++mi)
    #pragma unroll
    for (int ni = 0; ni < 4; ++ni) acc[mi][ni] = (f32x4){0.f, 0.f, 0.f, 0.f};

  for (int kt = 0; kt < K; kt += 32) {
    int u0 = t, u1 = t + 256;
    const ushort_t* ga0 = A + ((size_t)(m0 + (u0 >> 2)) * K + kt + (u0 & 3) * 8);
    const ushort_t* ga1 = A + ((size_t)(m0 + (u1 >> 2)) * K + kt + (u1 & 3) * 8);
    const ushort_t* gb0 = Bm + ((size_t)(n0 + (u0 >> 2)) * K + kt + (u0 & 3) * 8);
    const ushort_t* gb1 = Bm + ((size_t)(n0 + (u1 >> 2)) * K + kt + (u1 & 3) * 8);
    __builtin_amdgcn_global_load_lds((const AS1 void*)ga0, (AS3 void*)&As[(size_t)u0 * 8], 16, 0, 0);
    __builtin_amdgcn_global_load_lds((const AS1 void*)ga1, (AS3 void*)&As[(size_t)u1 * 8], 16, 0, 0);
    __builtin_amdgcn_global_load_lds((const AS1 void*)gb0, (AS3 void*)&Bs[(size_t)u0 * 8], 16, 0, 0);
    __builtin_amdgcn_global_load_lds((const AS1 void*)gb1, (AS3 void*)&Bs[(size_t)u1 * 8], 16, 0, 0);
    __syncthreads();
    bf16x8 af[4], bfr[4];
    #pragma unroll
    for (int mi = 0; mi < 4; ++mi)
      af[mi] = *(const bf16x8*)&As[(wm * 64 + mi * 16 + lo) * 32 + hi * 8];
    #pragma unroll
    for (int ni = 0; ni < 4; ++ni)
      bfr[ni] = *(const bf16x8*)&Bs[(wn * 64 + ni * 16 + lo) * 32 + hi * 8];
    #pragma unroll
    for (int mi = 0; mi < 4; ++mi)
      #pragma unroll
      for (int ni = 0; ni < 4; ++ni)
        acc[mi][ni] = __builtin_amdgcn_mfma_f32_16x16x32_bf16(af[mi], bfr[ni], acc[mi][ni], 0, 0, 0);
    __syncthreads();
  }

  // epilogue. D layout: col = lane&15, row = (lane>>4)*4 + j  [m89-verified]
  #pragma unroll
  for (int mi = 0; mi < 4; ++mi) {
    int rbase = m0 + wm * 64 + mi * 16 + hi * 4;
    #pragma unroll
    for (int ni = 0; ni < 4; ++ni) {
      int c = n0 + wn * 64 + ni * 16 + lo;
      f32x4 v = acc[mi][ni];
      if (EPI == 0) {
        int sec = c / 768;
        int cc = c - sec * 768;
        int h = cc >> 7, dd = cc & 127;
        #pragma unroll
        for (int j = 0; j < 4; ++j) {
          int r = rbase + j;
          int b = r >> 10, l = r & 1023;
          size_t bh = (size_t)(b * H_ + h);
          if (sec == 0)      qo[(bh * L_ + l) * D_ + dd] = f2bf(v[j] * 0.08838834764831845f);
          else if (sec == 1) ko[(bh * L_ + l) * D_ + dd] = f2bf(v[j]);
          else {
            ushort_t bv = f2bf(v[j]);
            vTo[(bh * D_ + dd) * L_ + l] = bv;
            vo[(bh * L_ + l) * D_ + dd] = bv;
          }
        }
      } else {
        #pragma unroll
        for (int j = 0; j < 4; ++j)
          fo[(size_t)(rbase + j) * N + c] = v[j];
      }
    }
  }
}

// ------------------------------------------------- flash attention w/ masks
// Swapped-QK^T 32x32 structure: 1 wave / 32 q-rows. S^T = mfma(K,Q) puts one
// q-row per lane (q = lane&31); softmax fully in-register (1 shfl_xor(32) per
// reduce). P->PV A-frags built in-register via half-swap (shfl_xor + select,
// == permlane32_swap). K/V frags direct from L2 with register prefetch
// (K one chunk ahead, V half a chunk ahead). No LDS, no barriers.
// C/D layout 32x32 [m74-verified]: col = lane&31, row = (r&3)+8*(r>>2)+4*(lane>>5).
__global__ __launch_bounds__(64)
void attn_kernel(const ushort_t* __restrict__ q, const ushort_t* __restrict__ k,
                 const ushort_t* __restrict__ vT, const ushort_t* __restrict__ v,
                 ushort_t* __restrict__ obf,
                 const u64* __restrict__ a1p, const u64* __restrict__ a2p,
                 const u64* __restrict__ d2p, const u64* __restrict__ d3p) {
  int lane = threadIdx.x;
  int lo32 = lane & 31, hi2 = lane >> 5;
  int bh = blockIdx.x, qt = blockIdx.y;
  int b = bh / H_, h = bh - b * H_;
  int qbase = qt * 32;

  if (h == 0) {
    // eye mask: out = v[l]  (h*D_ == 0 in output)
    const ushort_t* vp0 = v + ((size_t)bh * L_ + qbase) * D_;
    ushort_t* op0 = obf + ((size_t)b * L_ + qbase) * C_;
    #pragma unroll
    for (int i = 0; i < 8; ++i) {
      int u = i * 64 + lane;
      int r = u >> 4, c = (u & 15) * 8;
      *(bf16x8*)(op0 + (size_t)r * C_ + c) = *(const bf16x8*)(vp0 + (size_t)r * D_ + c);
    }
    return;
  }

  const ushort_t* qp = q + (size_t)bh * L_ * D_;
  const ushort_t* kp = k + (size_t)bh * L_ * D_;
  const ushort_t* vp = vT + (size_t)bh * D_ * L_;

  // Q B-frags hoisted: slot (hi2,e) of tile dt ~ Q[qbase+lo32][dt*16+hi2*8+e]
  bf16x8 qf[8];
  #pragma unroll
  for (int dt = 0; dt < 8; ++dt)
    qf[dt] = *(const bf16x8*)(qp + (size_t)(qbase + lo32) * D_ + dt * 16 + hi2 * 8);

  const u64* mp = (h == 1) ? a1p : (h == 2) ? a2p : (h == 3) ? d2p : d3p;
  bool full = (h == 5);
  const u64* mrow = mp + ((size_t)b * L_ + qbase + lo32) * 16;

  float m_run = NEGINF, l_run = 0.f;
  f32x16 acc[4];
  #pragma unroll
  for (int dt = 0; dt < 4; ++dt)
    #pragma unroll
    for (int r = 0; r < 16; ++r) acc[dt][r] = 0.f;

  // K A-frags for chunk 0 (prefetched one chunk ahead thereafter)
  bf16x8 kf[8];
  #pragma unroll
  for (int dt = 0; dt < 8; ++dt)
    kf[dt] = *(const bf16x8*)(kp + (size_t)lo32 * D_ + dt * 16 + hi2 * 8);

  u64 mw = 0;
  for (int ch = 0; ch < 32; ++ch) {
    int kc0 = ch * 32;
    // V B-frags for this chunk: consumed at PV (end of chunk) -> latency hidden
    bf16x8 vf[8];
    #pragma unroll
    for (int s = 0; s < 2; ++s)
      #pragma unroll
      for (int dt = 0; dt < 4; ++dt)
        vf[s * 4 + dt] = *(const bf16x8*)(vp + (size_t)(dt * 32 + lo32) * L_ + kc0 + s * 16 + hi2 * 8);
    // mask word for this 64-k pair of chunks
    if (!full && (ch & 1) == 0) mw = mrow[ch >> 1];
    uint_t mbits = full ? 0xffffffffu : (uint_t)(mw >> ((ch & 1) * 32));

    // S^T: sacc[r] = S[q = lo32][kc0 + (r&3)+8*(r>>2)+4*hi2]
    f32x16 sacc;
    #pragma unroll
    for (int r = 0; r < 16; ++r) sacc[r] = 0.f;
    #pragma unroll
    for (int dt = 0; dt < 8; ++dt)
      sacc = __builtin_amdgcn_mfma_f32_32x32x16_bf16(kf[dt], qf[dt], sacc, 0, 0, 0);

    // prefetch next chunk's K frags (consumed next iteration)
    if (ch < 31) {
      #pragma unroll
      for (int dt = 0; dt < 8; ++dt)
        kf[dt] = *(const bf16x8*)(kp + (size_t)(kc0 + 32 + lo32) * D_ + dt * 16 + hi2 * 8);
    }

    // mask select
    float sv[16];
    #pragma unroll
    for (int r = 0; r < 16; ++r) {
      int shift = (r & 3) + 8 * (r >> 2) + hi2 * 4;
      sv[r] = ((mbits >> shift) & 1u) ? sacc[r] : NEGINF;
    }

    // in-lane max tree + partner combine (1 cross-lane op)
    float a8[8];
    #pragma unroll
    for (int j = 0; j < 8; ++j) a8[j] = fmaxf(sv[2 * j], sv[2 * j + 1]);
    #pragma unroll
    for (int j = 0; j < 4; ++j) a8[j] = fmaxf(a8[j], a8[j + 4]);
    float pmax = fmaxf(fmaxf(a8[0], a8[1]), fmaxf(a8[2], a8[3]));
    pmax = fmaxf(pmax, __shfl_xor(pmax, 32));

    // defer-max (T13): rescale only when some row grew past THR
    if (__any(pmax > m_run + THR_)) {
      float mn = fmaxf(m_run, pmax);
      float corr = __expf(m_run - mn);
      l_run *= corr;
      m_run = mn;
      float cT[16];
      #pragma unroll
      for (int r = 0; r < 16; ++r)
        cT[r] = __shfl(corr, (r & 3) + 8 * (r >> 2) + hi2 * 4);
      #pragma unroll
      for (int dt = 0; dt < 4; ++dt)
        #pragma unroll
        for (int r = 0; r < 16; ++r) acc[dt][r] *= cT[r];
    }

    // P = exp(S - m_run); row-sum (in-lane tree + 1 cross-lane)
    float p[16];
    #pragma unroll
    for (int r = 0; r < 16; ++r) p[r] = __expf(sv[r] - m_run);
    float s8[8];
    #pragma unroll
    for (int j = 0; j < 8; ++j) s8[j] = p[2 * j] + p[2 * j + 1];
    #pragma unroll
    for (int j = 0; j < 4; ++j) s8[j] = s8[j] + s8[j + 4];
    float rs = (s8[0] + s8[1]) + (s8[2] + s8[3]);
    rs += __shfl_xor(rs, 32);
    l_run += rs;

    // pack P to bf16 words; half-swap to build PV A-frags (k = 16s+8*hi2+e)
    uint_t ow[8];
    #pragma unroll
    for (int j = 0; j < 8; ++j)
      ow[j] = (uint_t)f2bf(p[2 * j]) | ((uint_t)f2bf(p[2 * j + 1]) << 16);
    uint_t pw[8];
    #pragma unroll
    for (int j = 0; j < 8; ++j) pw[j] = __shfl_xor(ow[j], 32);
    u32x4 pa0 = (u32x4){hi2 ? pw[2] : ow[0], hi2 ? pw[3] : ow[1],
                        hi2 ? ow[2] : pw[0], hi2 ? ow[3] : pw[1]};
    u32x4 pa1 = (u32x4){hi2 ? pw[6] : ow[4], hi2 ? pw[7] : ow[5],
                        hi2 ? ow[6] : pw[4], hi2 ? ow[7] : pw[5]};
    bf16x8 paf0 = __builtin_bit_cast(bf16x8, pa0);
    bf16x8 paf1 = __builtin_bit_cast(bf16x8, pa1);

    // PV: acc[dt] += pa . V   (acc row = q via A-layout, col = d)
    #pragma unroll
    for (int dt = 0; dt < 4; ++dt) {
      acc[dt] = __builtin_amdgcn_mfma_f32_32x32x16_bf16(paf0, vf[dt], acc[dt], 0, 0, 0);
      acc[dt] = __builtin_amdgcn_mfma_f32_32x32x16_bf16(paf1, vf[4 + dt], acc[dt], 0, 0, 0);
    }
  }

  // epilogue: O /= l (transpose inv into C-layout), write bf16
  float inv = 1.f / l_run;
  float iT[16];
  #pragma unroll
  for (int r = 0; r < 16; ++r)
    iT[r] = __shfl(inv, (r & 3) + 8 * (r >> 2) + hi2 * 4);
  #pragma unroll
  for (int dt = 0; dt < 4; ++dt)
    #pragma unroll
    for (int r = 0; r < 16; ++r) {
      int qrow = qbase + (r & 3) + 8 * (r >> 2) + hi2 * 4;
      obf[((size_t)b * L_ + qrow) * C_ + h * D_ + dt * 32 + lo32] = f2bf(acc[dt][r] * iT[r]);
    }
}

// ---------------------------------------------------------------- launcher
extern "C" void kernel_launch(void* const* d_in, const int* in_sizes, int n_in,
                              void* d_out, int out_size, void* d_ws, size_t ws_size,
                              hipStream_t stream) {
  const float* x     = (const float*)d_in[0];
  const int*   adj   = (const int*)d_in[1];
  const int*   dist  = (const int*)d_in[2];
  const float* wqkv  = (const float*)d_in[3];
  const float* wproj = (const float*)d_in[4];
  float* out = (float*)d_out;
  char* ws = (char*)d_ws;

  const size_t SZ_X   = (size_t)B_ * L_ * C_ * 2;        // 12.6 MB
  const size_t SZ_WQ  = (size_t)3 * C_ * C_ * 2;
  const size_t SZ_WP  = (size_t)C_ * C_ * 2;
  const size_t SZ_QKV = (size_t)BH_ * L_ * D_ * 2;       // 12.6 MB
  const size_t SZ_MSK = (size_t)B_ * L_ * 16 * 8;        // 1 MB
  size_t off = 0;
  ushort_t* xbf  = (ushort_t*)(ws + off); off += SZ_X;
  ushort_t* wqb  = (ushort_t*)(ws + off); off += SZ_WQ;
  ushort_t* wpb  = (ushort_t*)(ws + off); off += SZ_WP;
  ushort_t* qb   = (ushort_t*)(ws + off); off += SZ_QKV;
  ushort_t* kb   = (ushort_t*)(ws + off); off += SZ_QKV;
  ushort_t* vTb  = (ushort_t*)(ws + off); off += SZ_QKV;
  ushort_t* vb   = (ushort_t*)(ws + off); off += SZ_QKV;
  ushort_t* ob   = (ushort_t*)(ws + off); off += SZ_X;
  u64* a1p = (u64*)(ws + off); off += SZ_MSK;
  u64* a2p = (u64*)(ws + off); off += SZ_MSK;
  u64* d2p = (u64*)(ws + off); off += SZ_MSK;
  u64* d3p = (u64*)(ws + off); off += SZ_MSK;
  (void)ws_size; (void)n_in; (void)in_sizes; (void)out_size;

  cvt_f32_bf16<<<(B_ * L_ * C_ / 8 + 255) / 256, 256, 0, stream>>>(x, xbf, B_ * L_ * C_ / 8);
  cvt_f32_bf16<<<(3 * C_ * C_ / 8 + 255) / 256, 256, 0, stream>>>(wqkv, wqb, 3 * C_ * C_ / 8);
  cvt_f32_bf16<<<(C_ * C_ / 8 + 255) / 256, 256, 0, stream>>>(wproj, wpb, C_ * C_ / 8);
  pack_masks<<<dim3(L_, B_), 256, 0, stream>>>(adj, dist, a1p, d2p, d3p);
  hop2<<<B_ * L_ / 64, 64, 0, stream>>>(a1p, a2p);
  // qkv = x @ wqkv^T  (M=8192, N=2304, K=768)
  gemm_bt<0><<<dim3(3 * C_ / 128, B_ * L_ / 128), 256, 0, stream>>>(
      xbf, wqb, 3 * C_, C_, qb, kb, vTb, vb, nullptr);
  // attention: 1 wave / 32 q-rows; grid (bh, qt) keeps bh's K/V on one XCD
  attn_kernel<<<dim3(BH_, L_ / 32), 64, 0, stream>>>(qb, kb, vTb, vb, ob, a1p, a2p, d2p, d3p);
  // out = O @ wproj^T  (M=8192, N=768, K=768)
  gemm_bt<1><<<dim3(C_ / 128, B_ * L_ / 128), 256, 0, stream>>>(
      ob, wpb, C_, C_, nullptr, nullptr, nullptr, nullptr, out);
}

// Round 7
// 221.707 us; speedup vs baseline: 1.2494x; 1.2494x over previous
//
#include <hip/hip_runtime.h>

typedef unsigned short ushort_t;
typedef unsigned int uint_t;
typedef unsigned long long u64;
typedef __attribute__((ext_vector_type(8))) short bf16x8;
typedef __attribute__((ext_vector_type(4))) float f32x4;

#define B_ 8
#define L_ 1024
#define C_ 768
#define H_ 6
#define D_ 128
#define BH_ 48
#define NEGINF (-1e9f)

#define AS1 __attribute__((address_space(1)))
#define AS3 __attribute__((address_space(3)))

// round-to-nearest-even f32 -> bf16
__device__ __forceinline__ ushort_t f2bf(float f) {
  uint_t u = __builtin_bit_cast(uint_t, f);
  u += 0x7fffu + ((u >> 16) & 1u);
  return (ushort_t)(u >> 16);
}

// ---------------------------------------------------------------- converts
__global__ void cvt_f32_bf16(const float* __restrict__ in, ushort_t* __restrict__ out, int n8) {
  int i = blockIdx.x * 256 + threadIdx.x;
  if (i >= n8) return;
  const float4* p = (const float4*)in + (size_t)i * 2;
  float4 a = p[0], b = p[1];
  uint4 r;
  r.x = (uint_t)f2bf(a.x) | ((uint_t)f2bf(a.y) << 16);
  r.y = (uint_t)f2bf(a.z) | ((uint_t)f2bf(a.w) << 16);
  r.z = (uint_t)f2bf(b.x) | ((uint_t)f2bf(b.y) << 16);
  r.w = (uint_t)f2bf(b.z) | ((uint_t)f2bf(b.w) << 16);
  ((uint4*)out)[i] = r;
}

// ------------------------------------------------- bit-pack a1 / d<=2 / d<=3
__global__ __launch_bounds__(256)
void pack_masks(const int* __restrict__ adj, const int* __restrict__ dist,
                u64* __restrict__ a1p, u64* __restrict__ d2p, u64* __restrict__ d3p) {
  int l = blockIdx.x, b = blockIdx.y, t = threadIdx.x;
  size_t base = ((size_t)b * L_ + l) * L_;
  size_t rb = ((size_t)b * L_ + l) * 16;
  #pragma unroll
  for (int it = 0; it < 4; ++it) {
    int c = it * 256 + t;
    int av = adj[base + c];
    int dv = dist[base + c];
    u64 m1 = __ballot((av > 0) || (c == l));
    u64 m2 = __ballot(dv <= 2);
    u64 m3 = __ballot(dv <= 3);
    if ((t & 63) == 0) {
      int w = it * 4 + (t >> 6);
      a1p[rb + w] = m1; d2p[rb + w] = m2; d3p[rb + w] = m3;
    }
  }
}

// ------------------------------------------------- 2-hop closure (bit OR)
__global__ __launch_bounds__(64)
void hop2(const u64* __restrict__ a1p, u64* __restrict__ a2p) {
  int tid = blockIdx.x * 64 + threadIdx.x;   // 0..8191 = (b,l)
  int b = tid >> 10;
  size_t rb = (size_t)tid * 16;
  u64 row[16], acc[16];
  #pragma unroll
  for (int j = 0; j < 16; ++j) { row[j] = a1p[rb + j]; acc[j] = 0ULL; }
  bool done = false;
  #pragma unroll
  for (int mw = 0; mw < 16; ++mw) {
    if (done) continue;
    u64 bits = row[mw];
    while (bits) {
      int tz = __builtin_ctzll(bits); bits &= bits - 1;
      const u64* src = a1p + (((size_t)b << 10) + (mw << 6) + tz) * 16;
      u64 band = ~0ULL;
      #pragma unroll
      for (int j = 0; j < 16; ++j) { acc[j] |= src[j]; band &= acc[j]; }
      if (band == ~0ULL) { done = true; break; }
    }
  }
  #pragma unroll
  for (int j = 0; j < 16; ++j) a2p[rb + j] = acc[j];
}

// ------------------------------------------------- bf16 GEMM  C = A @ B^T
// 128x128 tile, BK=64 (12 K-steps at K=768), 32 MFMA per barrier-pair.
// T2 both-sides XOR swizzle: linear LDS dest via global_load_lds, source
// col16 ^= row&7, ds_read slot ^= row&7 -> conflict-free (2-way).
// Bijective XCD swizzle on flattened block id (nwg % 8 == 0 for both calls).
template<int EPI>
__global__ __launch_bounds__(256)
void gemm_bt(const ushort_t* __restrict__ A, const ushort_t* __restrict__ Bm,
             int N, int K,
             ushort_t* __restrict__ qo, ushort_t* __restrict__ ko,
             ushort_t* __restrict__ vTo, ushort_t* __restrict__ vo,
             float* __restrict__ fo) {
  __shared__ __align__(16) ushort_t As[128 * 64];   // 16 KB
  __shared__ __align__(16) ushort_t Bs[128 * 64];   // 16 KB
  int t = threadIdx.x;
  int lane = t & 63, lo = lane & 15, hi = lane >> 4;
  int wv = t >> 6, wm = wv >> 1, wn = wv & 1;

  // XCD swizzle: consecutive remapped ids land on one XCD's L2
  int gx = gridDim.x;
  int nwg = gx * gridDim.y;
  int orig = blockIdx.y * gx + blockIdx.x;
  int cpx = nwg >> 3;
  int wg = (orig & 7) * cpx + (orig >> 3);
  int n0 = (wg % gx) * 128;
  int m0 = (wg / gx) * 128;

  f32x4 acc[4][4];
  #pragma unroll
  for (int mi = 0; mi < 4; ++mi)
    #pragma unroll
    for (int ni = 0; ni < 4; ++ni) acc[mi][ni] = (f32x4){0.f, 0.f, 0.f, 0.f};

  for (int kt = 0; kt < K; kt += 64) {
    #pragma unroll
    for (int i = 0; i < 4; ++i) {
      int u = i * 256 + t;                 // 0..1023
      int row = u >> 3, c16 = u & 7;
      int sc = c16 ^ (row & 7);
      __builtin_amdgcn_global_load_lds(
          (const AS1 void*)(A + ((size_t)(m0 + row) * K + kt + sc * 8)),
          (AS3 void*)&As[(size_t)u * 8], 16, 0, 0);
      __builtin_amdgcn_global_load_lds(
          (const AS1 void*)(Bm + ((size_t)(n0 + row) * K + kt + sc * 8)),
          (AS3 void*)&Bs[(size_t)u * 8], 16, 0, 0);
    }
    __syncthreads();
    #pragma unroll
    for (int kks = 0; kks < 2; ++kks) {
      bf16x8 af[4], bfr[4];
      #pragma unroll
      for (int mi = 0; mi < 4; ++mi) {
        int r = wm * 64 + mi * 16 + lo;
        af[mi] = *(const bf16x8*)&As[r * 64 + (((kks * 4 + hi) ^ (r & 7)) * 8)];
      }
      #pragma unroll
      for (int ni = 0; ni < 4; ++ni) {
        int r = wn * 64 + ni * 16 + lo;
        bfr[ni] = *(const bf16x8*)&Bs[r * 64 + (((kks * 4 + hi) ^ (r & 7)) * 8)];
      }
      #pragma unroll
      for (int mi = 0; mi < 4; ++mi)
        #pragma unroll
        for (int ni = 0; ni < 4; ++ni)
          acc[mi][ni] = __builtin_amdgcn_mfma_f32_16x16x32_bf16(af[mi], bfr[ni], acc[mi][ni], 0, 0, 0);
    }
    __syncthreads();
  }

  // epilogue. D layout: col = lane&15, row = (lane>>4)*4 + j  [m89-verified]
  #pragma unroll
  for (int mi = 0; mi < 4; ++mi) {
    int rbase = m0 + wm * 64 + mi * 16 + hi * 4;
    #pragma unroll
    for (int ni = 0; ni < 4; ++ni) {
      int c = n0 + wn * 64 + ni * 16 + lo;
      f32x4 v = acc[mi][ni];
      if (EPI == 0) {
        int sec = c / 768;
        int cc = c - sec * 768;
        int h = cc >> 7, dd = cc & 127;
        #pragma unroll
        for (int j = 0; j < 4; ++j) {
          int r = rbase + j;
          int b = r >> 10, l = r & 1023;
          size_t bh = (size_t)(b * H_ + h);
          if (sec == 0)      qo[(bh * L_ + l) * D_ + dd] = f2bf(v[j] * 0.08838834764831845f);
          else if (sec == 1) ko[(bh * L_ + l) * D_ + dd] = f2bf(v[j]);
          else {
            ushort_t bv = f2bf(v[j]);
            vTo[(bh * D_ + dd) * L_ + l] = bv;
            vo[(bh * L_ + l) * D_ + dd] = bv;
          }
        }
      } else {
        #pragma unroll
        for (int j = 0; j < 4; ++j)
          fo[(size_t)(rbase + j) * N + c] = v[j];
      }
    }
  }
}

// ------------------------------------------------- flash attention w/ masks
// R3 structure, KVBLK=32: LDS 36 KB -> 3 blocks/CU resident = 12 waves/CU
// (was 8). Double-buffered K/V staging (stage ch+1 before compute ch, one
// __syncthreads per chunk), mask u64 pipelined per pair of chunks.
__global__ __launch_bounds__(256)
void attn_kernel(const ushort_t* __restrict__ q, const ushort_t* __restrict__ k,
                 const ushort_t* __restrict__ vT, const ushort_t* __restrict__ v,
                 ushort_t* __restrict__ obf,
                 const u64* __restrict__ a1p, const u64* __restrict__ a2p,
                 const u64* __restrict__ d2p, const u64* __restrict__ d3p) {
  __shared__ __align__(16) ushort_t Ks[2][32 * 128];   // [krow][d], swizzled 16B blocks
  __shared__ __align__(16) ushort_t Vs[2][128 * 32];   // [d][kcol], swizzled 16B blocks
  __shared__ __align__(16) ushort_t Plds[4][16 * 32];  // per-wave P bounce, 4 KB
  int t = threadIdx.x;
  int lane = t & 63, lo = lane & 15, hi = lane >> 4, wv = t >> 6;
  int bh = blockIdx.x, qt = blockIdx.y;
  int b = bh / H_, h = bh - b * H_;
  int qbase = qt * 64;          // block's q range
  int qw = qbase + wv * 16;     // this wave's q range

  if (h == 0) {
    // eye mask: softmax over the single diagonal element -> out = v[l]
    const ushort_t* vp0 = v + ((size_t)bh * L_ + qbase) * D_;
    #pragma unroll
    for (int it = 0; it < 4; ++it) {
      int r = it * 16 + (t >> 4);
      int cpos = (t & 15) * 8;
      bf16x8 val = *(const bf16x8*)(vp0 + (size_t)r * D_ + cpos);
      *(bf16x8*)(obf + ((size_t)b * L_ + qbase + r) * C_ + cpos) = val; // h*D_ == 0
    }
    return;
  }

  const ushort_t* qp = q + ((size_t)bh * L_ + qw) * D_;
  const ushort_t* kp = k + (size_t)bh * L_ * D_;
  const ushort_t* vp = vT + (size_t)bh * D_ * L_;

  bf16x8 aq[4];
  #pragma unroll
  for (int kk = 0; kk < 4; ++kk)
    aq[kk] = *(const bf16x8*)(qp + (size_t)lo * D_ + kk * 32 + hi * 8);

  const u64* mp = (h == 1) ? a1p : (h == 2) ? a2p : (h == 3) ? d2p : d3p;
  bool full = (h == 5);
  const u64* mrow = mp + ((size_t)b * L_ + qw + hi * 4) * 16;

  float m_run[4], l_run[4];
  f32x4 acc_o[8];
  #pragma unroll
  for (int j = 0; j < 4; ++j) { m_run[j] = NEGINF; l_run[j] = 0.f; }
  #pragma unroll
  for (int nt = 0; nt < 8; ++nt) acc_o[nt] = (f32x4){0.f, 0.f, 0.f, 0.f};

  // stage one 32-col K/V chunk: 4 global_load_lds per thread
  auto stage = [&](int buf, int ch) {
    int kc0 = ch * 32;
    #pragma unroll
    for (int i = 0; i < 2; ++i) {
      int u = i * 256 + t;                 // 0..511
      int row = u >> 4, c16 = u & 15;      // K: 32 rows x 16 slots
      int sc16 = c16 ^ (row & 7);
      __builtin_amdgcn_global_load_lds(
          (const AS1 void*)(kp + (size_t)(kc0 + row) * D_ + sc16 * 8),
          (AS3 void*)&Ks[buf][(size_t)u * 8], 16, 0, 0);
    }
    #pragma unroll
    for (int i = 0; i < 2; ++i) {
      int u = i * 256 + t;                 // 0..511
      int row = u >> 2, c16 = u & 3;       // V: 128 rows x 4 slots
      int sc16 = c16 ^ (row & 3);
      __builtin_amdgcn_global_load_lds(
          (const AS1 void*)(vp + (size_t)row * L_ + kc0 + sc16 * 8),
          (AS3 void*)&Vs[buf][(size_t)u * 8], 16, 0, 0);
    }
  };

  // prologue: stage chunk 0; mask pair 0 (+ prefetch handled in-loop)
  stage(0, 0);
  u64 wm_pair[4] = {0, 0, 0, 0}, wm_np[4] = {0, 0, 0, 0};
  if (!full) {
    #pragma unroll
    for (int j = 0; j < 4; ++j) wm_pair[j] = mrow[j * 16 + 0];
  }
  __syncthreads();

  for (int ch = 0; ch < 32; ++ch) {
    int cur = ch & 1;
    // prefetch next chunk's stage before compute (latency hidden)
    if (ch < 31) stage(cur ^ 1, ch + 1);
    // mask pair rotation + prefetch (pair p = ch>>1, u64 covers 2 chunks)
    if (!full && (ch & 1) == 0) {
      if (ch > 0) {
        #pragma unroll
        for (int j = 0; j < 4; ++j) wm_pair[j] = wm_np[j];
      }
      if ((ch >> 1) < 15) {
        #pragma unroll
        for (int j = 0; j < 4; ++j) wm_np[j] = mrow[j * 16 + (ch >> 1) + 1];
      }
    }
    uint_t mhalf[4];
    #pragma unroll
    for (int j = 0; j < 4; ++j)
      mhalf[j] = full ? 0xffffffffu : (uint_t)(wm_pair[j] >> ((ch & 1) * 32));

    const ushort_t* ks = &Ks[cur][0];
    const ushort_t* vs = &Vs[cur][0];

    // S tile: rows qw+hi*4+j, cols ch*32 + st*16 + lo
    float sv[2][4];
    #pragma unroll
    for (int st = 0; st < 2; ++st) {
      f32x4 s = (f32x4){0.f, 0.f, 0.f, 0.f};
      int krow = st * 16 + lo;
      #pragma unroll
      for (int kk = 0; kk < 4; ++kk) {
        int c16s = (kk * 4 + hi) ^ (krow & 7);
        bf16x8 bk = *(const bf16x8*)&ks[krow * 128 + c16s * 8];
        s = __builtin_amdgcn_mfma_f32_16x16x32_bf16(aq[kk], bk, s, 0, 0, 0);
      }
      #pragma unroll
      for (int j = 0; j < 4; ++j) {
        bool bit = (mhalf[j] >> (st * 16 + lo)) & 1u;
        sv[st][j] = bit ? s[j] : NEGINF;
      }
    }
    // online softmax per row j
    float corr[4], pv[2][4];
    #pragma unroll
    for (int j = 0; j < 4; ++j) {
      float mx = fmaxf(sv[0][j], sv[1][j]);
      #pragma unroll
      for (int o = 8; o >= 1; o >>= 1) mx = fmaxf(mx, __shfl_xor(mx, o, 16));
      float mn = fmaxf(m_run[j], mx);
      corr[j] = __expf(m_run[j] - mn);
      float rs = 0.f;
      #pragma unroll
      for (int st = 0; st < 2; ++st) { float pp = __expf(sv[st][j] - mn); pv[st][j] = pp; rs += pp; }
      #pragma unroll
      for (int o = 8; o >= 1; o >>= 1) rs += __shfl_xor(rs, o, 16);
      l_run[j] = l_run[j] * corr[j] + rs;
      m_run[j] = mn;
    }
    f32x4 corrv = (f32x4){corr[0], corr[1], corr[2], corr[3]};
    #pragma unroll
    for (int nt = 0; nt < 8; ++nt) acc_o[nt] *= corrv;

    // P -> per-wave LDS (XOR-swizzled 4-slot rows), read back as A-frag
    char* pb = (char*)&Plds[wv][0];
    #pragma unroll
    for (int st = 0; st < 2; ++st)
      #pragma unroll
      for (int j = 0; j < 4; ++j) {
        int prow = hi * 4 + j;
        int addr = (prow * 64 + (st * 16 + lo) * 2) ^ ((prow & 3) << 4);
        *(ushort_t*)(pb + addr) = f2bf(pv[st][j]);
      }
    bf16x8 pa = *(const bf16x8*)(pb + lo * 64 + (((hi ^ (lo & 3)) << 4)));
    // PV: one MFMA per nt (K=32 covers the whole chunk)
    #pragma unroll
    for (int nt = 0; nt < 8; ++nt) {
      int vrow = nt * 16 + lo;
      int c16s = hi ^ (vrow & 3);
      bf16x8 bv = *(const bf16x8*)&vs[vrow * 32 + c16s * 8];
      acc_o[nt] = __builtin_amdgcn_mfma_f32_16x16x32_bf16(pa, bv, acc_o[nt], 0, 0, 0);
    }
    // one barrier per chunk: all waves done reading buf[cur]; buf[cur] may be
    // overwritten by next iteration's stage.
    __syncthreads();
  }
  // epilogue
  float inv[4];
  #pragma unroll
  for (int j = 0; j < 4; ++j) inv[j] = 1.f / l_run[j];
  #pragma unroll
  for (int nt = 0; nt < 8; ++nt)
    #pragma unroll
    for (int j = 0; j < 4; ++j)
      obf[((size_t)b * L_ + qw + hi * 4 + j) * C_ + h * D_ + nt * 16 + lo] =
          f2bf(acc_o[nt][j] * inv[j]);
}

// ---------------------------------------------------------------- launcher
extern "C" void kernel_launch(void* const* d_in, const int* in_sizes, int n_in,
                              void* d_out, int out_size, void* d_ws, size_t ws_size,
                              hipStream_t stream) {
  const float* x     = (const float*)d_in[0];
  const int*   adj   = (const int*)d_in[1];
  const int*   dist  = (const int*)d_in[2];
  const float* wqkv  = (const float*)d_in[3];
  const float* wproj = (const float*)d_in[4];
  float* out = (float*)d_out;
  char* ws = (char*)d_ws;

  const size_t SZ_X   = (size_t)B_ * L_ * C_ * 2;        // 12.6 MB
  const size_t SZ_WQ  = (size_t)3 * C_ * C_ * 2;
  const size_t SZ_WP  = (size_t)C_ * C_ * 2;
  const size_t SZ_QKV = (size_t)BH_ * L_ * D_ * 2;       // 12.6 MB
  const size_t SZ_MSK = (size_t)B_ * L_ * 16 * 8;        // 1 MB
  size_t off = 0;
  ushort_t* xbf  = (ushort_t*)(ws + off); off += SZ_X;
  ushort_t* wqb  = (ushort_t*)(ws + off); off += SZ_WQ;
  ushort_t* wpb  = (ushort_t*)(ws + off); off += SZ_WP;
  ushort_t* qb   = (ushort_t*)(ws + off); off += SZ_QKV;
  ushort_t* kb   = (ushort_t*)(ws + off); off += SZ_QKV;
  ushort_t* vTb  = (ushort_t*)(ws + off); off += SZ_QKV;
  ushort_t* vb   = (ushort_t*)(ws + off); off += SZ_QKV;
  ushort_t* ob   = (ushort_t*)(ws + off); off += SZ_X;
  u64* a1p = (u64*)(ws + off); off += SZ_MSK;
  u64* a2p = (u64*)(ws + off); off += SZ_MSK;
  u64* d2p = (u64*)(ws + off); off += SZ_MSK;
  u64* d3p = (u64*)(ws + off); off += SZ_MSK;
  (void)ws_size; (void)n_in; (void)in_sizes; (void)out_size;

  cvt_f32_bf16<<<(B_ * L_ * C_ / 8 + 255) / 256, 256, 0, stream>>>(x, xbf, B_ * L_ * C_ / 8);
  cvt_f32_bf16<<<(3 * C_ * C_ / 8 + 255) / 256, 256, 0, stream>>>(wqkv, wqb, 3 * C_ * C_ / 8);
  cvt_f32_bf16<<<(C_ * C_ / 8 + 255) / 256, 256, 0, stream>>>(wproj, wpb, C_ * C_ / 8);
  pack_masks<<<dim3(L_, B_), 256, 0, stream>>>(adj, dist, a1p, d2p, d3p);
  hop2<<<B_ * L_ / 64, 64, 0, stream>>>(a1p, a2p);
  // qkv = x @ wqkv^T  (M=8192, N=2304, K=768), nwg=1152 (%8==0)
  gemm_bt<0><<<dim3(3 * C_ / 128, B_ * L_ / 128), 256, 0, stream>>>(
      xbf, wqb, 3 * C_, C_, qb, kb, vTb, vb, nullptr);
  // attention: grid (bh, qt) for XCD pinning of each bh's K/V
  attn_kernel<<<dim3(BH_, L_ / 64), 256, 0, stream>>>(qb, kb, vTb, vb, ob, a1p, a2p, d2p, d3p);
  // out = O @ wproj^T  (M=8192, N=768, K=768), nwg=384 (%8==0)
  gemm_bt<1><<<dim3(C_ / 128, B_ * L_ / 128), 256, 0, stream>>>(
      ob, wpb, C_, C_, nullptr, nullptr, nullptr, nullptr, out);
}

// Round 8
// 221.265 us; speedup vs baseline: 1.2519x; 1.0020x over previous
//
#include <hip/hip_runtime.h>

typedef unsigned short ushort_t;
typedef unsigned int uint_t;
typedef unsigned long long u64;
typedef __attribute__((ext_vector_type(8))) short bf16x8;
typedef __attribute__((ext_vector_type(4))) float f32x4;
typedef __attribute__((ext_vector_type(16))) float f32x16;
typedef __attribute__((ext_vector_type(4))) uint_t u32x4;

#define B_ 8
#define L_ 1024
#define C_ 768
#define H_ 6
#define D_ 128
#define BH_ 48
#define NEGINF (-1e9f)
#define THR_ 8.0f

#define AS1 __attribute__((address_space(1)))
#define AS3 __attribute__((address_space(3)))

// round-to-nearest-even f32 -> bf16
__device__ __forceinline__ ushort_t f2bf(float f) {
  uint_t u = __builtin_bit_cast(uint_t, f);
  u += 0x7fffu + ((u >> 16) & 1u);
  return (ushort_t)(u >> 16);
}

// ---------------------------------------------------------------- converts
__global__ void cvt_f32_bf16(const float* __restrict__ in, ushort_t* __restrict__ out, int n8) {
  int i = blockIdx.x * 256 + threadIdx.x;
  if (i >= n8) return;
  const float4* p = (const float4*)in + (size_t)i * 2;
  float4 a = p[0], b = p[1];
  uint4 r;
  r.x = (uint_t)f2bf(a.x) | ((uint_t)f2bf(a.y) << 16);
  r.y = (uint_t)f2bf(a.z) | ((uint_t)f2bf(a.w) << 16);
  r.z = (uint_t)f2bf(b.x) | ((uint_t)f2bf(b.y) << 16);
  r.w = (uint_t)f2bf(b.z) | ((uint_t)f2bf(b.w) << 16);
  ((uint4*)out)[i] = r;
}

// ------------------------------------------------- bit-pack a1 / d<=2 / d<=3
__global__ __launch_bounds__(256)
void pack_masks(const int* __restrict__ adj, const int* __restrict__ dist,
                u64* __restrict__ a1p, u64* __restrict__ d2p, u64* __restrict__ d3p) {
  int l = blockIdx.x, b = blockIdx.y, t = threadIdx.x;
  size_t base = ((size_t)b * L_ + l) * L_;
  size_t rb = ((size_t)b * L_ + l) * 16;
  #pragma unroll
  for (int it = 0; it < 4; ++it) {
    int c = it * 256 + t;
    int av = adj[base + c];
    int dv = dist[base + c];
    u64 m1 = __ballot((av > 0) || (c == l));
    u64 m2 = __ballot(dv <= 2);
    u64 m3 = __ballot(dv <= 3);
    if ((t & 63) == 0) {
      int w = it * 4 + (t >> 6);
      a1p[rb + w] = m1; d2p[rb + w] = m2; d3p[rb + w] = m3;
    }
  }
}

// ------------------------------------------------- 2-hop closure (bit OR)
__global__ __launch_bounds__(64)
void hop2(const u64* __restrict__ a1p, u64* __restrict__ a2p) {
  int tid = blockIdx.x * 64 + threadIdx.x;   // 0..8191 = (b,l)
  int b = tid >> 10;
  size_t rb = (size_t)tid * 16;
  u64 row[16], acc[16];
  #pragma unroll
  for (int j = 0; j < 16; ++j) { row[j] = a1p[rb + j]; acc[j] = 0ULL; }
  bool done = false;
  #pragma unroll
  for (int mw = 0; mw < 16; ++mw) {
    if (done) continue;
    u64 bits = row[mw];
    while (bits) {
      int tz = __builtin_ctzll(bits); bits &= bits - 1;
      const u64* src = a1p + (((size_t)b << 10) + (mw << 6) + tz) * 16;
      u64 band = ~0ULL;
      #pragma unroll
      for (int j = 0; j < 16; ++j) { acc[j] |= src[j]; band &= acc[j]; }
      if (band == ~0ULL) { done = true; break; }
    }
  }
  #pragma unroll
  for (int j = 0; j < 16; ++j) a2p[rb + j] = acc[j];
}

// ------------------------------------------------- bf16 GEMM  C = A @ B^T
// 128x128 tile, BK=64, T2 both-sides XOR swizzle, bijective XCD swizzle.
template<int EPI>
__global__ __launch_bounds__(256)
void gemm_bt(const ushort_t* __restrict__ A, const ushort_t* __restrict__ Bm,
             int N, int K,
             ushort_t* __restrict__ qo, ushort_t* __restrict__ ko,
             ushort_t* __restrict__ vTo, ushort_t* __restrict__ vo,
             float* __restrict__ fo) {
  __shared__ __align__(16) ushort_t As[128 * 64];   // 16 KB
  __shared__ __align__(16) ushort_t Bs[128 * 64];   // 16 KB
  int t = threadIdx.x;
  int lane = t & 63, lo = lane & 15, hi = lane >> 4;
  int wv = t >> 6, wm = wv >> 1, wn = wv & 1;

  int gx = gridDim.x;
  int nwg = gx * gridDim.y;
  int orig = blockIdx.y * gx + blockIdx.x;
  int cpx = nwg >> 3;
  int wg = (orig & 7) * cpx + (orig >> 3);
  int n0 = (wg % gx) * 128;
  int m0 = (wg / gx) * 128;

  f32x4 acc[4][4];
  #pragma unroll
  for (int mi = 0; mi < 4; ++mi)
    #pragma unroll
    for (int ni = 0; ni < 4; ++ni) acc[mi][ni] = (f32x4){0.f, 0.f, 0.f, 0.f};

  for (int kt = 0; kt < K; kt += 64) {
    #pragma unroll
    for (int i = 0; i < 4; ++i) {
      int u = i * 256 + t;                 // 0..1023
      int row = u >> 3, c16 = u & 7;
      int sc = c16 ^ (row & 7);
      __builtin_amdgcn_global_load_lds(
          (const AS1 void*)(A + ((size_t)(m0 + row) * K + kt + sc * 8)),
          (AS3 void*)&As[(size_t)u * 8], 16, 0, 0);
      __builtin_amdgcn_global_load_lds(
          (const AS1 void*)(Bm + ((size_t)(n0 + row) * K + kt + sc * 8)),
          (AS3 void*)&Bs[(size_t)u * 8], 16, 0, 0);
    }
    __syncthreads();
    #pragma unroll
    for (int kks = 0; kks < 2; ++kks) {
      bf16x8 af[4], bfr[4];
      #pragma unroll
      for (int mi = 0; mi < 4; ++mi) {
        int r = wm * 64 + mi * 16 + lo;
        af[mi] = *(const bf16x8*)&As[r * 64 + (((kks * 4 + hi) ^ (r & 7)) * 8)];
      }
      #pragma unroll
      for (int ni = 0; ni < 4; ++ni) {
        int r = wn * 64 + ni * 16 + lo;
        bfr[ni] = *(const bf16x8*)&Bs[r * 64 + (((kks * 4 + hi) ^ (r & 7)) * 8)];
      }
      #pragma unroll
      for (int mi = 0; mi < 4; ++mi)
        #pragma unroll
        for (int ni = 0; ni < 4; ++ni)
          acc[mi][ni] = __builtin_amdgcn_mfma_f32_16x16x32_bf16(af[mi], bfr[ni], acc[mi][ni], 0, 0, 0);
    }
    __syncthreads();
  }

  // epilogue. D layout: col = lane&15, row = (lane>>4)*4 + j  [m89-verified]
  #pragma unroll
  for (int mi = 0; mi < 4; ++mi) {
    int rbase = m0 + wm * 64 + mi * 16 + hi * 4;
    #pragma unroll
    for (int ni = 0; ni < 4; ++ni) {
      int c = n0 + wn * 64 + ni * 16 + lo;
      f32x4 v = acc[mi][ni];
      if (EPI == 0) {
        int sec = c / 768;
        int cc = c - sec * 768;
        int h = cc >> 7, dd = cc & 127;
        #pragma unroll
        for (int j = 0; j < 4; ++j) {
          int r = rbase + j;
          int b = r >> 10, l = r & 1023;
          size_t bh = (size_t)(b * H_ + h);
          if (sec == 0)      qo[(bh * L_ + l) * D_ + dd] = f2bf(v[j] * 0.08838834764831845f);
          else if (sec == 1) ko[(bh * L_ + l) * D_ + dd] = f2bf(v[j]);
          else {
            ushort_t bv = f2bf(v[j]);
            vTo[(bh * D_ + dd) * L_ + l] = bv;
            vo[(bh * L_ + l) * D_ + dd] = bv;
          }
        }
      } else {
        #pragma unroll
        for (int j = 0; j < 4; ++j)
          fo[(size_t)(rbase + j) * N + c] = v[j];
      }
    }
  }
}

// ------------------------------------------------- flash attention w/ masks
// Swapped-QK^T 32x32 (R6-verified layout algebra) + LDS staging (R3-verified
// schedule). 4 waves/block, each owns a 32-q tile; KVBLK=64 double-buffered.
// S^T = mfma(K,Q): lane owns q-row (lane&31); softmax fully in-register
// (in-lane trees + 1 shfl_xor(32)); P->A-frags via half-swap; no P-LDS.
// K frag reads: 16-slot XOR row&15 (2-way, free); V^T: 8-slot XOR row&7.
__global__ __launch_bounds__(256)
void attn_kernel(const ushort_t* __restrict__ q, const ushort_t* __restrict__ k,
                 const ushort_t* __restrict__ vT, const ushort_t* __restrict__ v,
                 ushort_t* __restrict__ obf,
                 const u64* __restrict__ a1p, const u64* __restrict__ a2p,
                 const u64* __restrict__ d2p, const u64* __restrict__ d3p) {
  __shared__ __align__(16) ushort_t Ks[2][64 * 128];   // [krow][d] 32 KB
  __shared__ __align__(16) ushort_t Vs[2][128 * 64];   // [d][kcol] 32 KB
  int t = threadIdx.x;
  int lane = t & 63, lo32 = lane & 31, hi2 = (lane >> 5) & 1, wv = t >> 6;
  int bh = blockIdx.x, qt = blockIdx.y;
  int b = bh / H_, h = bh - b * H_;
  int qbase = qt * 128;           // block's q range (4 waves x 32)
  int qw = qbase + wv * 32;       // this wave's q tile

  if (h == 0) {
    // eye mask: out = v[l]  (h*D_ == 0 in output)
    const ushort_t* vp0 = v + ((size_t)bh * L_ + qbase) * D_;
    ushort_t* op0 = obf + ((size_t)b * L_ + qbase) * C_;
    #pragma unroll
    for (int it = 0; it < 8; ++it) {
      int u = it * 256 + t;
      int r = u >> 4, c = (u & 15) * 8;
      *(bf16x8*)(op0 + (size_t)r * C_ + c) = *(const bf16x8*)(vp0 + (size_t)r * D_ + c);
    }
    return;
  }

  const ushort_t* qp = q + (size_t)bh * L_ * D_;
  const ushort_t* kp = k + (size_t)bh * L_ * D_;
  const ushort_t* vp = vT + (size_t)bh * D_ * L_;

  // Q B-frags (one-time): B[k=d][n=q]; lane holds Q[qw+lo32][dt*16+hi2*8+e]
  bf16x8 qf[8];
  #pragma unroll
  for (int dt = 0; dt < 8; ++dt)
    qf[dt] = *(const bf16x8*)(qp + (size_t)(qw + lo32) * D_ + dt * 16 + hi2 * 8);

  const u64* mp = (h == 1) ? a1p : (h == 2) ? a2p : (h == 3) ? d2p : d3p;
  bool full = (h == 5);
  const u64* mrow = mp + ((size_t)b * L_ + qw + lo32) * 16;

  float m_run = NEGINF, l_run = 0.f;
  f32x16 acc[4];
  #pragma unroll
  for (int dt = 0; dt < 4; ++dt)
    #pragma unroll
    for (int r = 0; r < 16; ++r) acc[dt][r] = 0.f;

  // stage one 64-col K/V chunk: 8 global_load_lds per thread, linear LDS dest,
  // XOR-swizzled global source (K: 16 slots ^ row&15; V: 8 slots ^ row&7)
  auto stage = [&](int buf, int ch) {
    int kc0 = ch * 64;
    #pragma unroll
    for (int i = 0; i < 4; ++i) {
      int u = i * 256 + t;                 // K: 64 rows x 16 slots
      int row = u >> 4, c16 = u & 15;
      int sc = c16 ^ (row & 15);
      __builtin_amdgcn_global_load_lds(
          (const AS1 void*)(kp + (size_t)(kc0 + row) * D_ + sc * 8),
          (AS3 void*)&Ks[buf][(size_t)u * 8], 16, 0, 0);
    }
    #pragma unroll
    for (int i = 0; i < 4; ++i) {
      int u = i * 256 + t;                 // V: 128 rows x 8 slots
      int row = u >> 3, c16 = u & 7;
      int sc = c16 ^ (row & 7);
      __builtin_amdgcn_global_load_lds(
          (const AS1 void*)(vp + (size_t)row * L_ + kc0 + sc * 8),
          (AS3 void*)&Vs[buf][(size_t)u * 8], 16, 0, 0);
    }
  };

  stage(0, 0);
  u64 mw_cur = full ? 0ULL : mrow[0];
  __syncthreads();

  for (int ch = 0; ch < 16; ++ch) {
    int cur = ch & 1;
    if (ch < 15) stage(cur ^ 1, ch + 1);            // prefetch next chunk
    u64 mw_nxt = (!full && ch < 15) ? mrow[ch + 1] : 0ULL;

    const ushort_t* ks = &Ks[cur][0];
    const ushort_t* vs = &Vs[cur][0];

    #pragma unroll
    for (int s = 0; s < 2; ++s) {                   // two 32-k subtiles
      // S^T subtile: sacc[r] = S[q=lo32][64ch + 32s + crow(r,hi2)]
      f32x16 sacc;
      #pragma unroll
      for (int r = 0; r < 16; ++r) sacc[r] = 0.f;
      __builtin_amdgcn_s_setprio(1);
      #pragma unroll
      for (int dt = 0; dt < 8; ++dt) {
        int krow = s * 32 + lo32;
        int c16 = (dt * 2 + hi2) ^ (krow & 15);
        bf16x8 kf = *(const bf16x8*)&ks[krow * 128 + c16 * 8];
        sacc = __builtin_amdgcn_mfma_f32_32x32x16_bf16(kf, qf[dt], sacc, 0, 0, 0);
      }
      __builtin_amdgcn_s_setprio(0);

      uint_t mbits = full ? 0xffffffffu : (uint_t)(mw_cur >> (32 * s));
      float sv[16];
      #pragma unroll
      for (int r = 0; r < 16; ++r) {
        int shift = (r & 3) + 8 * (r >> 2) + hi2 * 4;
        sv[r] = ((mbits >> shift) & 1u) ? sacc[r] : NEGINF;
      }

      // in-lane max tree + 1 cross-lane
      float a8[8];
      #pragma unroll
      for (int j = 0; j < 8; ++j) a8[j] = fmaxf(sv[2 * j], sv[2 * j + 1]);
      #pragma unroll
      for (int j = 0; j < 4; ++j) a8[j] = fmaxf(a8[j], a8[j + 4]);
      float pmax = fmaxf(fmaxf(a8[0], a8[1]), fmaxf(a8[2], a8[3]));
      pmax = fmaxf(pmax, __shfl_xor(pmax, 32));

      // defer-max (T13)
      if (__any(pmax > m_run + THR_)) {
        float mn = fmaxf(m_run, pmax);
        float corr = __expf(m_run - mn);
        l_run *= corr;
        m_run = mn;
        float cT[16];
        #pragma unroll
        for (int r = 0; r < 16; ++r)
          cT[r] = __shfl(corr, (r & 3) + 8 * (r >> 2) + hi2 * 4);
        #pragma unroll
        for (int dt = 0; dt < 4; ++dt)
          #pragma unroll
          for (int r = 0; r < 16; ++r) acc[dt][r] *= cT[r];
      }

      // P = exp(S - m_run); row-sum
      float p[16];
      #pragma unroll
      for (int r = 0; r < 16; ++r) p[r] = __expf(sv[r] - m_run);
      float s8[8];
      #pragma unroll
      for (int j = 0; j < 8; ++j) s8[j] = p[2 * j] + p[2 * j + 1];
      #pragma unroll
      for (int j = 0; j < 4; ++j) s8[j] = s8[j] + s8[j + 4];
      float rs = (s8[0] + s8[1]) + (s8[2] + s8[3]);
      rs += __shfl_xor(rs, 32);
      l_run += rs;

      // pack P; half-swap to build PV A-frags (R6-verified)
      uint_t ow[8];
      #pragma unroll
      for (int j = 0; j < 8; ++j)
        ow[j] = (uint_t)f2bf(p[2 * j]) | ((uint_t)f2bf(p[2 * j + 1]) << 16);
      uint_t pw[8];
      #pragma unroll
      for (int j = 0; j < 8; ++j) pw[j] = __shfl_xor(ow[j], 32);
      u32x4 pa0 = (u32x4){hi2 ? pw[2] : ow[0], hi2 ? pw[3] : ow[1],
                          hi2 ? ow[2] : pw[0], hi2 ? ow[3] : pw[1]};
      u32x4 pa1 = (u32x4){hi2 ? pw[6] : ow[4], hi2 ? pw[7] : ow[5],
                          hi2 ? ow[6] : pw[4], hi2 ? ow[7] : pw[5]};
      bf16x8 paf0 = __builtin_bit_cast(bf16x8, pa0);
      bf16x8 paf1 = __builtin_bit_cast(bf16x8, pa1);

      // PV: B-frags from swizzled Vs; paf0 ~ k-slice 0..15, paf1 ~ 16..31
      __builtin_amdgcn_s_setprio(1);
      #pragma unroll
      for (int dt = 0; dt < 4; ++dt) {
        int vd = dt * 32 + lo32;
        int c16a = (s * 4 + hi2) ^ (vd & 7);
        int c16b = (s * 4 + 2 + hi2) ^ (vd & 7);
        bf16x8 vfa = *(const bf16x8*)&vs[vd * 64 + c16a * 8];
        bf16x8 vfb = *(const bf16x8*)&vs[vd * 64 + c16b * 8];
        acc[dt] = __builtin_amdgcn_mfma_f32_32x32x16_bf16(paf0, vfa, acc[dt], 0, 0, 0);
        acc[dt] = __builtin_amdgcn_mfma_f32_32x32x16_bf16(paf1, vfb, acc[dt], 0, 0, 0);
      }
      __builtin_amdgcn_s_setprio(0);
    }
    mw_cur = mw_nxt;
    // all waves done reading buf[cur]; safe to overwrite next iteration
    __syncthreads();
  }

  // epilogue: O /= l (broadcast per C-row), write bf16
  float inv = 1.f / l_run;
  float iT[16];
  #pragma unroll
  for (int r = 0; r < 16; ++r)
    iT[r] = __shfl(inv, (r & 3) + 8 * (r >> 2) + hi2 * 4);
  #pragma unroll
  for (int dt = 0; dt < 4; ++dt)
    #pragma unroll
    for (int r = 0; r < 16; ++r) {
      int qrow = qw + (r & 3) + 8 * (r >> 2) + hi2 * 4;
      obf[((size_t)b * L_ + qrow) * C_ + h * D_ + dt * 32 + lo32] = f2bf(acc[dt][r] * iT[r]);
    }
}

// ---------------------------------------------------------------- launcher
extern "C" void kernel_launch(void* const* d_in, const int* in_sizes, int n_in,
                              void* d_out, int out_size, void* d_ws, size_t ws_size,
                              hipStream_t stream) {
  const float* x     = (const float*)d_in[0];
  const int*   adj   = (const int*)d_in[1];
  const int*   dist  = (const int*)d_in[2];
  const float* wqkv  = (const float*)d_in[3];
  const float* wproj = (const float*)d_in[4];
  float* out = (float*)d_out;
  char* ws = (char*)d_ws;

  const size_t SZ_X   = (size_t)B_ * L_ * C_ * 2;        // 12.6 MB
  const size_t SZ_WQ  = (size_t)3 * C_ * C_ * 2;
  const size_t SZ_WP  = (size_t)C_ * C_ * 2;
  const size_t SZ_QKV = (size_t)BH_ * L_ * D_ * 2;       // 12.6 MB
  const size_t SZ_MSK = (size_t)B_ * L_ * 16 * 8;        // 1 MB
  size_t off = 0;
  ushort_t* xbf  = (ushort_t*)(ws + off); off += SZ_X;
  ushort_t* wqb  = (ushort_t*)(ws + off); off += SZ_WQ;
  ushort_t* wpb  = (ushort_t*)(ws + off); off += SZ_WP;
  ushort_t* qb   = (ushort_t*)(ws + off); off += SZ_QKV;
  ushort_t* kb   = (ushort_t*)(ws + off); off += SZ_QKV;
  ushort_t* vTb  = (ushort_t*)(ws + off); off += SZ_QKV;
  ushort_t* vb   = (ushort_t*)(ws + off); off += SZ_QKV;
  ushort_t* ob   = (ushort_t*)(ws + off); off += SZ_X;
  u64* a1p = (u64*)(ws + off); off += SZ_MSK;
  u64* a2p = (u64*)(ws + off); off += SZ_MSK;
  u64* d2p = (u64*)(ws + off); off += SZ_MSK;
  u64* d3p = (u64*)(ws + off); off += SZ_MSK;
  (void)ws_size; (void)n_in; (void)in_sizes; (void)out_size;

  cvt_f32_bf16<<<(B_ * L_ * C_ / 8 + 255) / 256, 256, 0, stream>>>(x, xbf, B_ * L_ * C_ / 8);
  cvt_f32_bf16<<<(3 * C_ * C_ / 8 + 255) / 256, 256, 0, stream>>>(wqkv, wqb, 3 * C_ * C_ / 8);
  cvt_f32_bf16<<<(C_ * C_ / 8 + 255) / 256, 256, 0, stream>>>(wproj, wpb, C_ * C_ / 8);
  pack_masks<<<dim3(L_, B_), 256, 0, stream>>>(adj, dist, a1p, d2p, d3p);
  hop2<<<B_ * L_ / 64, 64, 0, stream>>>(a1p, a2p);
  // qkv = x @ wqkv^T  (M=8192, N=2304, K=768), nwg=1152 (%8==0)
  gemm_bt<0><<<dim3(3 * C_ / 128, B_ * L_ / 128), 256, 0, stream>>>(
      xbf, wqb, 3 * C_, C_, qb, kb, vTb, vb, nullptr);
  // attention: 4 waves/block x 32 q-rows; grid (bh, qt) pins bh's K/V per XCD
  attn_kernel<<<dim3(BH_, L_ / 128), 256, 0, stream>>>(qb, kb, vTb, vb, ob, a1p, a2p, d2p, d3p);
  // out = O @ wproj^T  (M=8192, N=768, K=768), nwg=384 (%8==0)
  gemm_bt<1><<<dim3(C_ / 128, B_ * L_ / 128), 256, 0, stream>>>(
      ob, wpb, C_, C_, nullptr, nullptr, nullptr, nullptr, out);
}

// Round 9
// 216.177 us; speedup vs baseline: 1.2814x; 1.0235x over previous
//
#include <hip/hip_runtime.h>

typedef unsigned short ushort_t;
typedef unsigned int uint_t;
typedef unsigned long long u64;
typedef __attribute__((ext_vector_type(8))) short bf16x8;
typedef __attribute__((ext_vector_type(4))) float f32x4;
typedef __attribute__((ext_vector_type(16))) float f32x16;
typedef __attribute__((ext_vector_type(4))) uint_t u32x4;

#define B_ 8
#define L_ 1024
#define C_ 768
#define H_ 6
#define D_ 128
#define BH_ 48
#define NEGINF (-1e9f)
#define THR_ 8.0f

#define AS1 __attribute__((address_space(1)))
#define AS3 __attribute__((address_space(3)))

// round-to-nearest-even f32 -> bf16
__device__ __forceinline__ ushort_t f2bf(float f) {
  uint_t u = __builtin_bit_cast(uint_t, f);
  u += 0x7fffu + ((u >> 16) & 1u);
  return (ushort_t)(u >> 16);
}
__device__ __forceinline__ float bf2f(ushort_t s) {
  uint_t u = ((uint_t)s) << 16;
  return __builtin_bit_cast(float, u);
}

// ---------------------------------------------------------------- converts
__global__ void cvt_f32_bf16(const float* __restrict__ in, ushort_t* __restrict__ out, int n8) {
  int i = blockIdx.x * 256 + threadIdx.x;
  if (i >= n8) return;
  const float4* p = (const float4*)in + (size_t)i * 2;
  float4 a = p[0], b = p[1];
  uint4 r;
  r.x = (uint_t)f2bf(a.x) | ((uint_t)f2bf(a.y) << 16);
  r.y = (uint_t)f2bf(a.z) | ((uint_t)f2bf(a.w) << 16);
  r.z = (uint_t)f2bf(b.x) | ((uint_t)f2bf(b.y) << 16);
  r.w = (uint_t)f2bf(b.z) | ((uint_t)f2bf(b.w) << 16);
  ((uint4*)out)[i] = r;
}

// ------------------------------------------------- bit-pack a1 / d<=2 / d<=3
__global__ __launch_bounds__(256)
void pack_masks(const int* __restrict__ adj, const int* __restrict__ dist,
                u64* __restrict__ a1p, u64* __restrict__ d2p, u64* __restrict__ d3p) {
  int l = blockIdx.x, b = blockIdx.y, t = threadIdx.x;
  size_t base = ((size_t)b * L_ + l) * L_;
  size_t rb = ((size_t)b * L_ + l) * 16;
  #pragma unroll
  for (int it = 0; it < 4; ++it) {
    int c = it * 256 + t;
    int av = adj[base + c];
    int dv = dist[base + c];
    u64 m1 = __ballot((av > 0) || (c == l));
    u64 m2 = __ballot(dv <= 2);
    u64 m3 = __ballot(dv <= 3);
    if ((t & 63) == 0) {
      int w = it * 4 + (t >> 6);
      a1p[rb + w] = m1; d2p[rb + w] = m2; d3p[rb + w] = m3;
    }
  }
}

// ------------------------------------------------- 2-hop closure (bit OR)
__global__ __launch_bounds__(64)
void hop2(const u64* __restrict__ a1p, u64* __restrict__ a2p) {
  int tid = blockIdx.x * 64 + threadIdx.x;   // 0..8191 = (b,l)
  int b = tid >> 10;
  size_t rb = (size_t)tid * 16;
  u64 row[16], acc[16];
  #pragma unroll
  for (int j = 0; j < 16; ++j) { row[j] = a1p[rb + j]; acc[j] = 0ULL; }
  bool done = false;
  #pragma unroll
  for (int mw = 0; mw < 16; ++mw) {
    if (done) continue;
    u64 bits = row[mw];
    while (bits) {
      int tz = __builtin_ctzll(bits); bits &= bits - 1;
      const u64* src = a1p + (((size_t)b << 10) + (mw << 6) + tz) * 16;
      u64 band = ~0ULL;
      #pragma unroll
      for (int j = 0; j < 16; ++j) { acc[j] |= src[j]; band &= acc[j]; }
      if (band == ~0ULL) { done = true; break; }
    }
  }
  #pragma unroll
  for (int j = 0; j < 16; ++j) a2p[rb + j] = acc[j];
}

// ------------------------------------------------- bf16 GEMM  C = A @ B^T
// 128x128 tile, BK=64, T2 both-sides XOR swizzle, bijective XCD swizzle.
template<int EPI>
__global__ __launch_bounds__(256)
void gemm_bt(const ushort_t* __restrict__ A, const ushort_t* __restrict__ Bm,
             int N, int K,
             ushort_t* __restrict__ qo, ushort_t* __restrict__ ko,
             ushort_t* __restrict__ vTo, ushort_t* __restrict__ vo,
             float* __restrict__ fo) {
  __shared__ __align__(16) ushort_t As[128 * 64];   // 16 KB
  __shared__ __align__(16) ushort_t Bs[128 * 64];   // 16 KB
  int t = threadIdx.x;
  int lane = t & 63, lo = lane & 15, hi = lane >> 4;
  int wv = t >> 6, wm = wv >> 1, wn = wv & 1;

  int gx = gridDim.x;
  int nwg = gx * gridDim.y;
  int orig = blockIdx.y * gx + blockIdx.x;
  int cpx = nwg >> 3;
  int wg = (orig & 7) * cpx + (orig >> 3);
  int n0 = (wg % gx) * 128;
  int m0 = (wg / gx) * 128;

  f32x4 acc[4][4];
  #pragma unroll
  for (int mi = 0; mi < 4; ++mi)
    #pragma unroll
    for (int ni = 0; ni < 4; ++ni) acc[mi][ni] = (f32x4){0.f, 0.f, 0.f, 0.f};

  for (int kt = 0; kt < K; kt += 64) {
    #pragma unroll
    for (int i = 0; i < 4; ++i) {
      int u = i * 256 + t;                 // 0..1023
      int row = u >> 3, c16 = u & 7;
      int sc = c16 ^ (row & 7);
      __builtin_amdgcn_global_load_lds(
          (const AS1 void*)(A + ((size_t)(m0 + row) * K + kt + sc * 8)),
          (AS3 void*)&As[(size_t)u * 8], 16, 0, 0);
      __builtin_amdgcn_global_load_lds(
          (const AS1 void*)(Bm + ((size_t)(n0 + row) * K + kt + sc * 8)),
          (AS3 void*)&Bs[(size_t)u * 8], 16, 0, 0);
    }
    __syncthreads();
    #pragma unroll
    for (int kks = 0; kks < 2; ++kks) {
      bf16x8 af[4], bfr[4];
      #pragma unroll
      for (int mi = 0; mi < 4; ++mi) {
        int r = wm * 64 + mi * 16 + lo;
        af[mi] = *(const bf16x8*)&As[r * 64 + (((kks * 4 + hi) ^ (r & 7)) * 8)];
      }
      #pragma unroll
      for (int ni = 0; ni < 4; ++ni) {
        int r = wn * 64 + ni * 16 + lo;
        bfr[ni] = *(const bf16x8*)&Bs[r * 64 + (((kks * 4 + hi) ^ (r & 7)) * 8)];
      }
      #pragma unroll
      for (int mi = 0; mi < 4; ++mi)
        #pragma unroll
        for (int ni = 0; ni < 4; ++ni)
          acc[mi][ni] = __builtin_amdgcn_mfma_f32_16x16x32_bf16(af[mi], bfr[ni], acc[mi][ni], 0, 0, 0);
    }
    __syncthreads();
  }

  // epilogue. D layout: col = lane&15, row = (lane>>4)*4 + j  [m89-verified]
  #pragma unroll
  for (int mi = 0; mi < 4; ++mi) {
    int rbase = m0 + wm * 64 + mi * 16 + hi * 4;
    #pragma unroll
    for (int ni = 0; ni < 4; ++ni) {
      int c = n0 + wn * 64 + ni * 16 + lo;
      f32x4 v = acc[mi][ni];
      if (EPI == 0) {
        int sec = c / 768;
        int cc = c - sec * 768;
        int h = cc >> 7, dd = cc & 127;
        #pragma unroll
        for (int j = 0; j < 4; ++j) {
          int r = rbase + j;
          int b = r >> 10, l = r & 1023;
          size_t bh = (size_t)(b * H_ + h);
          if (sec == 0)      qo[(bh * L_ + l) * D_ + dd] = f2bf(v[j] * 0.08838834764831845f);
          else if (sec == 1) ko[(bh * L_ + l) * D_ + dd] = f2bf(v[j]);
          else {
            ushort_t bv = f2bf(v[j]);
            vTo[(bh * D_ + dd) * L_ + l] = bv;
            vo[(bh * L_ + l) * D_ + dd] = bv;
          }
        }
      } else {
        #pragma unroll
        for (int j = 0; j < 4; ++j)
          fo[(size_t)(rbase + j) * N + c] = v[j];
      }
    }
  }
}

// ------------------------------------------------- flash attention, split-K=2
// Swapped-QK^T 32x32 (R6/R8-verified), KVBLK=32, 4 waves x 32 q-rows / block.
// blockIdx.z = kv-half; each block covers kv [half*512, half*512+512) in 16
// chunks, writes UNNORMALIZED partial N = sum exp(S-m)V (bf16) + (m,l) f32.
// combine kernel merges halves. Valid for any reference m (defer-max safe);
// empty halves get m=-1e9 -> weight exp(m-M)=0 in combine.
__global__ __launch_bounds__(256)
void attn_kernel(const ushort_t* __restrict__ q, const ushort_t* __restrict__ k,
                 const ushort_t* __restrict__ vT, const ushort_t* __restrict__ v,
                 ushort_t* __restrict__ obf,
                 ushort_t* __restrict__ np0, ushort_t* __restrict__ np1,
                 float* __restrict__ ml,
                 const u64* __restrict__ a1p, const u64* __restrict__ a2p,
                 const u64* __restrict__ d2p, const u64* __restrict__ d3p) {
  __shared__ __align__(16) ushort_t Ks[2][32 * 128];   // [krow][d]  8 KB x2
  __shared__ __align__(16) ushort_t Vs[2][128 * 32];   // [d][kcol]  8 KB x2
  int t = threadIdx.x;
  int lane = t & 63, lo32 = lane & 31, hi2 = (lane >> 5) & 1, wv = t >> 6;
  int bh = blockIdx.x, qt = blockIdx.y, half = blockIdx.z;
  int b = bh / H_, h = bh - b * H_;
  int qbase = qt * 128;
  int qw = qbase + wv * 32;
  int kvb = half * 512;

  if (h == 0) {
    if (half) return;
    // eye mask: out = v[l]  (h*D_ == 0 in output)
    const ushort_t* vp0 = v + ((size_t)bh * L_ + qbase) * D_;
    ushort_t* op0 = obf + ((size_t)b * L_ + qbase) * C_;
    #pragma unroll
    for (int it = 0; it < 8; ++it) {
      int u = it * 256 + t;
      int r = u >> 4, c = (u & 15) * 8;
      *(bf16x8*)(op0 + (size_t)r * C_ + c) = *(const bf16x8*)(vp0 + (size_t)r * D_ + c);
    }
    return;
  }

  const ushort_t* qp = q + (size_t)bh * L_ * D_;
  const ushort_t* kp = k + (size_t)bh * L_ * D_ + (size_t)kvb * D_;
  const ushort_t* vp = vT + (size_t)bh * D_ * L_ + kvb;

  bf16x8 qf[8];
  #pragma unroll
  for (int dt = 0; dt < 8; ++dt)
    qf[dt] = *(const bf16x8*)(qp + (size_t)(qw + lo32) * D_ + dt * 16 + hi2 * 8);

  const u64* mp = (h == 1) ? a1p : (h == 2) ? a2p : (h == 3) ? d2p : d3p;
  bool full = (h == 5);
  const u64* mrow = mp + ((size_t)b * L_ + qw + lo32) * 16 + half * 8;

  float m_run = NEGINF, l_run = 0.f;
  f32x16 acc[4];
  #pragma unroll
  for (int dt = 0; dt < 4; ++dt)
    #pragma unroll
    for (int r = 0; r < 16; ++r) acc[dt][r] = 0.f;

  // stage one 32-col K/V chunk: 4 global_load_lds per thread
  auto stage = [&](int buf, int ch) {
    int kc0 = ch * 32;
    #pragma unroll
    for (int i = 0; i < 2; ++i) {
      int u = i * 256 + t;                 // K: 32 rows x 16 slots
      int row = u >> 4, c16 = u & 15;
      int sc = c16 ^ (row & 15);
      __builtin_amdgcn_global_load_lds(
          (const AS1 void*)(kp + (size_t)(kc0 + row) * D_ + sc * 8),
          (AS3 void*)&Ks[buf][(size_t)u * 8], 16, 0, 0);
    }
    #pragma unroll
    for (int i = 0; i < 2; ++i) {
      int u = i * 256 + t;                 // V: 128 rows x 4 slots
      int row = u >> 2, c16 = u & 3;
      int sc = c16 ^ (row & 3);
      __builtin_amdgcn_global_load_lds(
          (const AS1 void*)(vp + (size_t)row * L_ + kc0 + sc * 8),
          (AS3 void*)&Vs[buf][(size_t)u * 8], 16, 0, 0);
    }
  };

  stage(0, 0);
  u64 mw_cur = full ? 0ULL : mrow[0];
  u64 mw_nxt = 0ULL;
  __syncthreads();

  for (int ch = 0; ch < 16; ++ch) {
    int cur = ch & 1;
    if (ch < 15) stage(cur ^ 1, ch + 1);        // prefetch next chunk
    if (!full && (ch & 1) == 0 && (ch >> 1) + 1 < 8)
      mw_nxt = mrow[(ch >> 1) + 1];

    const ushort_t* ks = &Ks[cur][0];
    const ushort_t* vs = &Vs[cur][0];
    uint_t mbits = full ? 0xffffffffu : (uint_t)(mw_cur >> ((ch & 1) * 32));

    // S^T: sacc[r] = S[q=lo32][kvb + ch*32 + crow(r,hi2)]
    f32x16 sacc;
    #pragma unroll
    for (int r = 0; r < 16; ++r) sacc[r] = 0.f;
    __builtin_amdgcn_s_setprio(1);
    #pragma unroll
    for (int dt = 0; dt < 8; ++dt) {
      int c16 = (dt * 2 + hi2) ^ (lo32 & 15);
      bf16x8 kf = *(const bf16x8*)&ks[lo32 * 128 + c16 * 8];
      sacc = __builtin_amdgcn_mfma_f32_32x32x16_bf16(kf, qf[dt], sacc, 0, 0, 0);
    }
    __builtin_amdgcn_s_setprio(0);

    float sv[16];
    #pragma unroll
    for (int r = 0; r < 16; ++r) {
      int shift = (r & 3) + 8 * (r >> 2) + hi2 * 4;
      sv[r] = ((mbits >> shift) & 1u) ? sacc[r] : NEGINF;
    }

    // in-lane max tree + 1 cross-lane
    float a8[8];
    #pragma unroll
    for (int j = 0; j < 8; ++j) a8[j] = fmaxf(sv[2 * j], sv[2 * j + 1]);
    #pragma unroll
    for (int j = 0; j < 4; ++j) a8[j] = fmaxf(a8[j], a8[j + 4]);
    float pmax = fmaxf(fmaxf(a8[0], a8[1]), fmaxf(a8[2], a8[3]));
    pmax = fmaxf(pmax, __shfl_xor(pmax, 32));

    // defer-max (T13)
    if (__any(pmax > m_run + THR_)) {
      float mn = fmaxf(m_run, pmax);
      float corr = __expf(m_run - mn);
      l_run *= corr;
      m_run = mn;
      float cT[16];
      #pragma unroll
      for (int r = 0; r < 16; ++r)
        cT[r] = __shfl(corr, (r & 3) + 8 * (r >> 2) + hi2 * 4);
      #pragma unroll
      for (int dt = 0; dt < 4; ++dt)
        #pragma unroll
        for (int r = 0; r < 16; ++r) acc[dt][r] *= cT[r];
    }

    // P = exp(S - m_run); row-sum
    float p[16];
    #pragma unroll
    for (int r = 0; r < 16; ++r) p[r] = __expf(sv[r] - m_run);
    float s8[8];
    #pragma unroll
    for (int j = 0; j < 8; ++j) s8[j] = p[2 * j] + p[2 * j + 1];
    #pragma unroll
    for (int j = 0; j < 4; ++j) s8[j] = s8[j] + s8[j + 4];
    float rs = (s8[0] + s8[1]) + (s8[2] + s8[3]);
    rs += __shfl_xor(rs, 32);
    l_run += rs;

    // pack P; half-swap to build PV A-frags (R6/R8-verified)
    uint_t ow[8];
    #pragma unroll
    for (int j = 0; j < 8; ++j)
      ow[j] = (uint_t)f2bf(p[2 * j]) | ((uint_t)f2bf(p[2 * j + 1]) << 16);
    uint_t pw[8];
    #pragma unroll
    for (int j = 0; j < 8; ++j) pw[j] = __shfl_xor(ow[j], 32);
    u32x4 pa0 = (u32x4){hi2 ? pw[2] : ow[0], hi2 ? pw[3] : ow[1],
                        hi2 ? ow[2] : pw[0], hi2 ? ow[3] : pw[1]};
    u32x4 pa1 = (u32x4){hi2 ? pw[6] : ow[4], hi2 ? pw[7] : ow[5],
                        hi2 ? ow[6] : pw[4], hi2 ? ow[7] : pw[5]};
    bf16x8 paf0 = __builtin_bit_cast(bf16x8, pa0);
    bf16x8 paf1 = __builtin_bit_cast(bf16x8, pa1);

    // PV: paf0 ~ kv 0..15, paf1 ~ kv 16..31 of the chunk
    __builtin_amdgcn_s_setprio(1);
    #pragma unroll
    for (int dt = 0; dt < 4; ++dt) {
      int vd = dt * 32 + lo32;
      int c16a = hi2 ^ (vd & 3);
      int c16b = (2 + hi2) ^ (vd & 3);
      bf16x8 vfa = *(const bf16x8*)&vs[vd * 32 + c16a * 8];
      bf16x8 vfb = *(const bf16x8*)&vs[vd * 32 + c16b * 8];
      acc[dt] = __builtin_amdgcn_mfma_f32_32x32x16_bf16(paf0, vfa, acc[dt], 0, 0, 0);
      acc[dt] = __builtin_amdgcn_mfma_f32_32x32x16_bf16(paf1, vfb, acc[dt], 0, 0, 0);
    }
    __builtin_amdgcn_s_setprio(0);
    if (ch & 1) mw_cur = mw_nxt;
    __syncthreads();
  }

  // epilogue: write partials. (m,l) per q-row (hi2==0 lanes); N unnormalized bf16.
  if (hi2 == 0) {
    size_t row = (size_t)bh * L_ + qw + lo32;
    float2 v2 = make_float2(m_run, l_run);
    *(float2*)(ml + ((size_t)half * BH_ * L_ + row) * 2) = v2;
  }
  ushort_t* np = half ? np1 : np0;
  #pragma unroll
  for (int dt = 0; dt < 4; ++dt)
    #pragma unroll
    for (int r = 0; r < 16; ++r) {
      int qrow = qw + (r & 3) + 8 * (r >> 2) + hi2 * 4;
      np[((size_t)bh * L_ + qrow) * D_ + dt * 32 + lo32] = f2bf(acc[dt][r]);
    }
}

// ------------------------------------------------- split-K combine
__global__ __launch_bounds__(256)
void combine(const ushort_t* __restrict__ np0, const ushort_t* __restrict__ np1,
             const float* __restrict__ ml, ushort_t* __restrict__ obf) {
  int bh = blockIdx.x;
  int b = bh / H_, h = bh - b * H_;
  if (h == 0) return;                       // eye head written directly
  int t = threadIdx.x;
  int qi = t >> 4, di = t & 15;             // 16 q-rows x 16 d-groups of 8
  int qq = blockIdx.y * 16 + qi;
  size_t row = (size_t)bh * L_ + qq;
  float2 ml1 = *(const float2*)(ml + row * 2);
  float2 ml2 = *(const float2*)(ml + ((size_t)BH_ * L_ + row) * 2);
  float M = fmaxf(ml1.x, ml2.x);
  float w1 = __expf(ml1.x - M), w2 = __expf(ml2.x - M);
  float inv = 1.f / (w1 * ml1.y + w2 * ml2.y);
  bf16x8 n1 = *(const bf16x8*)(np0 + row * D_ + di * 8);
  bf16x8 n2 = *(const bf16x8*)(np1 + row * D_ + di * 8);
  ushort_t o[8];
  #pragma unroll
  for (int j = 0; j < 8; ++j)
    o[j] = f2bf((w1 * bf2f((ushort_t)n1[j]) + w2 * bf2f((ushort_t)n2[j])) * inv);
  *(bf16x8*)(obf + ((size_t)b * L_ + qq) * C_ + h * D_ + di * 8) = *(bf16x8*)o;
}

// ---------------------------------------------------------------- launcher
extern "C" void kernel_launch(void* const* d_in, const int* in_sizes, int n_in,
                              void* d_out, int out_size, void* d_ws, size_t ws_size,
                              hipStream_t stream) {
  const float* x     = (const float*)d_in[0];
  const int*   adj   = (const int*)d_in[1];
  const int*   dist  = (const int*)d_in[2];
  const float* wqkv  = (const float*)d_in[3];
  const float* wproj = (const float*)d_in[4];
  float* out = (float*)d_out;
  char* ws = (char*)d_ws;

  const size_t SZ_X   = (size_t)B_ * L_ * C_ * 2;        // 12.6 MB (== SZ_QKV)
  const size_t SZ_WQ  = (size_t)3 * C_ * C_ * 2;
  const size_t SZ_WP  = (size_t)C_ * C_ * 2;
  const size_t SZ_QKV = (size_t)BH_ * L_ * D_ * 2;       // 12.6 MB
  const size_t SZ_MSK = (size_t)B_ * L_ * 16 * 8;        // 1 MB
  const size_t SZ_ML  = (size_t)2 * BH_ * L_ * 2 * 4;    // 0.79 MB
  size_t off = 0;
  ushort_t* xbf  = (ushort_t*)(ws + off); off += SZ_X;   // reused as np0 post-GEMM
  ushort_t* wqb  = (ushort_t*)(ws + off); off += SZ_WQ;
  ushort_t* wpb  = (ushort_t*)(ws + off); off += SZ_WP;
  ushort_t* qb   = (ushort_t*)(ws + off); off += SZ_QKV;
  ushort_t* kb   = (ushort_t*)(ws + off); off += SZ_QKV;
  ushort_t* vTb  = (ushort_t*)(ws + off); off += SZ_QKV;
  ushort_t* vb   = (ushort_t*)(ws + off); off += SZ_QKV;
  ushort_t* ob   = (ushort_t*)(ws + off); off += SZ_X;
  u64* a1p = (u64*)(ws + off); off += SZ_MSK;
  u64* a2p = (u64*)(ws + off); off += SZ_MSK;
  u64* d2p = (u64*)(ws + off); off += SZ_MSK;
  u64* d3p = (u64*)(ws + off); off += SZ_MSK;
  ushort_t* np1 = (ushort_t*)(ws + off); off += SZ_QKV;  // partial N half 1
  float*    mlb = (float*)(ws + off); off += SZ_ML;      // (m,l)[2][BH][L]
  ushort_t* np0 = xbf;                                   // partial N half 0
  (void)ws_size; (void)n_in; (void)in_sizes; (void)out_size;

  cvt_f32_bf16<<<(B_ * L_ * C_ / 8 + 255) / 256, 256, 0, stream>>>(x, xbf, B_ * L_ * C_ / 8);
  cvt_f32_bf16<<<(3 * C_ * C_ / 8 + 255) / 256, 256, 0, stream>>>(wqkv, wqb, 3 * C_ * C_ / 8);
  cvt_f32_bf16<<<(C_ * C_ / 8 + 255) / 256, 256, 0, stream>>>(wproj, wpb, C_ * C_ / 8);
  pack_masks<<<dim3(L_, B_), 256, 0, stream>>>(adj, dist, a1p, d2p, d3p);
  hop2<<<B_ * L_ / 64, 64, 0, stream>>>(a1p, a2p);
  // qkv = x @ wqkv^T  (M=8192, N=2304, K=768), nwg=1152 (%8==0)
  gemm_bt<0><<<dim3(3 * C_ / 128, B_ * L_ / 128), 256, 0, stream>>>(
      xbf, wqb, 3 * C_, C_, qb, kb, vTb, vb, nullptr);
  // attention split-K=2: grid (bh, qt, half); bh fastest -> XCD pinning kept
  attn_kernel<<<dim3(BH_, L_ / 128, 2), 256, 0, stream>>>(
      qb, kb, vTb, vb, ob, np0, np1, mlb, a1p, a2p, d2p, d3p);
  combine<<<dim3(BH_, L_ / 16), 256, 0, stream>>>(np0, np1, mlb, ob);
  // out = O @ wproj^T  (M=8192, N=768, K=768), nwg=384 (%8==0)
  gemm_bt<1><<<dim3(C_ / 128, B_ * L_ / 128), 256, 0, stream>>>(
      ob, wpb, C_, C_, nullptr, nullptr, nullptr, nullptr, out);
}

// Round 10
// 203.727 us; speedup vs baseline: 1.3597x; 1.0611x over previous
//
#include <hip/hip_runtime.h>

typedef unsigned short ushort_t;
typedef unsigned int uint_t;
typedef unsigned long long u64;
typedef __attribute__((ext_vector_type(8))) short bf16x8;
typedef __attribute__((ext_vector_type(4))) float f32x4;
typedef __attribute__((ext_vector_type(16))) float f32x16;
typedef __attribute__((ext_vector_type(4))) uint_t u32x4;

#define B_ 8
#define L_ 1024
#define C_ 768
#define H_ 6
#define D_ 128
#define BH_ 48
#define NEGINF (-1e9f)
#define THR_ 8.0f

#define AS1 __attribute__((address_space(1)))
#define AS3 __attribute__((address_space(3)))

// round-to-nearest-even f32 -> bf16
__device__ __forceinline__ ushort_t f2bf(float f) {
  uint_t u = __builtin_bit_cast(uint_t, f);
  u += 0x7fffu + ((u >> 16) & 1u);
  return (ushort_t)(u >> 16);
}
__device__ __forceinline__ float bf2f(ushort_t s) {
  uint_t u = ((uint_t)s) << 16;
  return __builtin_bit_cast(float, u);
}

// ---------------------------------------------------------------- converts
__global__ void cvt_f32_bf16(const float* __restrict__ in, ushort_t* __restrict__ out, int n8) {
  int i = blockIdx.x * 256 + threadIdx.x;
  if (i >= n8) return;
  const float4* p = (const float4*)in + (size_t)i * 2;
  float4 a = p[0], b = p[1];
  uint4 r;
  r.x = (uint_t)f2bf(a.x) | ((uint_t)f2bf(a.y) << 16);
  r.y = (uint_t)f2bf(a.z) | ((uint_t)f2bf(a.w) << 16);
  r.z = (uint_t)f2bf(b.x) | ((uint_t)f2bf(b.y) << 16);
  r.w = (uint_t)f2bf(b.z) | ((uint_t)f2bf(b.w) << 16);
  ((uint4*)out)[i] = r;
}

// ------------------------------------------------- bit-pack a1 / d<=2 / d<=3
__global__ __launch_bounds__(256)
void pack_masks(const int* __restrict__ adj, const int* __restrict__ dist,
                u64* __restrict__ a1p, u64* __restrict__ d2p, u64* __restrict__ d3p) {
  int l = blockIdx.x, b = blockIdx.y, t = threadIdx.x;
  size_t base = ((size_t)b * L_ + l) * L_;
  size_t rb = ((size_t)b * L_ + l) * 16;
  #pragma unroll
  for (int it = 0; it < 4; ++it) {
    int c = it * 256 + t;
    int av = adj[base + c];
    int dv = dist[base + c];
    u64 m1 = __ballot((av > 0) || (c == l));
    u64 m2 = __ballot(dv <= 2);
    u64 m3 = __ballot(dv <= 3);
    if ((t & 63) == 0) {
      int w = it * 4 + (t >> 6);
      a1p[rb + w] = m1; d2p[rb + w] = m2; d3p[rb + w] = m3;
    }
  }
}

// ------------------------------------------------- 2-hop closure (bit OR)
__global__ __launch_bounds__(64)
void hop2(const u64* __restrict__ a1p, u64* __restrict__ a2p) {
  int tid = blockIdx.x * 64 + threadIdx.x;   // 0..8191 = (b,l)
  int b = tid >> 10;
  size_t rb = (size_t)tid * 16;
  u64 row[16], acc[16];
  #pragma unroll
  for (int j = 0; j < 16; ++j) { row[j] = a1p[rb + j]; acc[j] = 0ULL; }
  bool done = false;
  #pragma unroll
  for (int mw = 0; mw < 16; ++mw) {
    if (done) continue;
    u64 bits = row[mw];
    while (bits) {
      int tz = __builtin_ctzll(bits); bits &= bits - 1;
      const u64* src = a1p + (((size_t)b << 10) + (mw << 6) + tz) * 16;
      u64 band = ~0ULL;
      #pragma unroll
      for (int j = 0; j < 16; ++j) { acc[j] |= src[j]; band &= acc[j]; }
      if (band == ~0ULL) { done = true; break; }
    }
  }
  #pragma unroll
  for (int j = 0; j < 16; ++j) a2p[rb + j] = acc[j];
}

// ------------------------------------------------- bf16 GEMM  C = A @ B^T
// 128x128 tile, BK=64, T2 both-sides XOR swizzle, bijective XCD swizzle.
template<int EPI>
__global__ __launch_bounds__(256)
void gemm_bt(const ushort_t* __restrict__ A, const ushort_t* __restrict__ Bm,
             int N, int K,
             ushort_t* __restrict__ qo, ushort_t* __restrict__ ko,
             ushort_t* __restrict__ vTo, ushort_t* __restrict__ vo,
             float* __restrict__ fo) {
  __shared__ __align__(16) ushort_t As[128 * 64];   // 16 KB
  __shared__ __align__(16) ushort_t Bs[128 * 64];   // 16 KB
  int t = threadIdx.x;
  int lane = t & 63, lo = lane & 15, hi = lane >> 4;
  int wv = t >> 6, wm = wv >> 1, wn = wv & 1;

  int gx = gridDim.x;
  int nwg = gx * gridDim.y;
  int orig = blockIdx.y * gx + blockIdx.x;
  int cpx = nwg >> 3;
  int wg = (orig & 7) * cpx + (orig >> 3);
  int n0 = (wg % gx) * 128;
  int m0 = (wg / gx) * 128;

  f32x4 acc[4][4];
  #pragma unroll
  for (int mi = 0; mi < 4; ++mi)
    #pragma unroll
    for (int ni = 0; ni < 4; ++ni) acc[mi][ni] = (f32x4){0.f, 0.f, 0.f, 0.f};

  for (int kt = 0; kt < K; kt += 64) {
    #pragma unroll
    for (int i = 0; i < 4; ++i) {
      int u = i * 256 + t;                 // 0..1023
      int row = u >> 3, c16 = u & 7;
      int sc = c16 ^ (row & 7);
      __builtin_amdgcn_global_load_lds(
          (const AS1 void*)(A + ((size_t)(m0 + row) * K + kt + sc * 8)),
          (AS3 void*)&As[(size_t)u * 8], 16, 0, 0);
      __builtin_amdgcn_global_load_lds(
          (const AS1 void*)(Bm + ((size_t)(n0 + row) * K + kt + sc * 8)),
          (AS3 void*)&Bs[(size_t)u * 8], 16, 0, 0);
    }
    __syncthreads();
    #pragma unroll
    for (int kks = 0; kks < 2; ++kks) {
      bf16x8 af[4], bfr[4];
      #pragma unroll
      for (int mi = 0; mi < 4; ++mi) {
        int r = wm * 64 + mi * 16 + lo;
        af[mi] = *(const bf16x8*)&As[r * 64 + (((kks * 4 + hi) ^ (r & 7)) * 8)];
      }
      #pragma unroll
      for (int ni = 0; ni < 4; ++ni) {
        int r = wn * 64 + ni * 16 + lo;
        bfr[ni] = *(const bf16x8*)&Bs[r * 64 + (((kks * 4 + hi) ^ (r & 7)) * 8)];
      }
      #pragma unroll
      for (int mi = 0; mi < 4; ++mi)
        #pragma unroll
        for (int ni = 0; ni < 4; ++ni)
          acc[mi][ni] = __builtin_amdgcn_mfma_f32_16x16x32_bf16(af[mi], bfr[ni], acc[mi][ni], 0, 0, 0);
    }
    __syncthreads();
  }

  // epilogue. D layout: col = lane&15, row = (lane>>4)*4 + j  [m89-verified]
  #pragma unroll
  for (int mi = 0; mi < 4; ++mi) {
    int rbase = m0 + wm * 64 + mi * 16 + hi * 4;
    #pragma unroll
    for (int ni = 0; ni < 4; ++ni) {
      int c = n0 + wn * 64 + ni * 16 + lo;
      f32x4 v = acc[mi][ni];
      if (EPI == 0) {
        int sec = c / 768;
        int cc = c - sec * 768;
        int h = cc >> 7, dd = cc & 127;
        #pragma unroll
        for (int j = 0; j < 4; ++j) {
          int r = rbase + j;
          int b = r >> 10, l = r & 1023;
          size_t bh = (size_t)(b * H_ + h);
          if (sec == 0)      qo[(bh * L_ + l) * D_ + dd] = f2bf(v[j] * 0.08838834764831845f);
          else if (sec == 1) ko[(bh * L_ + l) * D_ + dd] = f2bf(v[j]);
          else {
            ushort_t bv = f2bf(v[j]);
            vTo[(bh * D_ + dd) * L_ + l] = bv;
            vo[(bh * L_ + l) * D_ + dd] = bv;
          }
        }
      } else {
        #pragma unroll
        for (int j = 0; j < 4; ++j)
          fo[(size_t)(rbase + j) * N + c] = v[j];
      }
    }
  }
}

// ------------------------------------------------- flash attention, split-K=2
// 8 waves / block, 256 q-rows (32/wave); kv half per blockIdx.z; KVBLK=32.
// Each staged chunk now feeds 8 waves (2x q-amortization vs R9); stage is
// 2 global_load_lds per thread (m97 shape). Inner loop identical to R9
// (swapped-QK^T 32x32, in-register softmax, half-swap P->A-frags).
__global__ __launch_bounds__(512)
void attn_kernel(const ushort_t* __restrict__ q, const ushort_t* __restrict__ k,
                 const ushort_t* __restrict__ vT, const ushort_t* __restrict__ v,
                 ushort_t* __restrict__ obf,
                 ushort_t* __restrict__ np0, ushort_t* __restrict__ np1,
                 float* __restrict__ ml,
                 const u64* __restrict__ a1p, const u64* __restrict__ a2p,
                 const u64* __restrict__ d2p, const u64* __restrict__ d3p) {
  __shared__ __align__(16) ushort_t Ks[2][32 * 128];   // [krow][d]  8 KB x2
  __shared__ __align__(16) ushort_t Vs[2][128 * 32];   // [d][kcol]  8 KB x2
  int t = threadIdx.x;
  int lane = t & 63, lo32 = lane & 31, hi2 = (lane >> 5) & 1, wv = t >> 6;
  int bh = blockIdx.x, qt = blockIdx.y, half = blockIdx.z;
  int b = bh / H_, h = bh - b * H_;
  int qbase = qt * 256;
  int qw = qbase + wv * 32;
  int kvb = half * 512;

  if (h == 0) {
    if (half) return;
    // eye mask: out = v[l]  (h*D_ == 0 in output)
    const ushort_t* vp0 = v + ((size_t)bh * L_ + qbase) * D_;
    ushort_t* op0 = obf + ((size_t)b * L_ + qbase) * C_;
    #pragma unroll
    for (int it = 0; it < 8; ++it) {
      int u = it * 512 + t;
      int r = u >> 4, c = (u & 15) * 8;
      *(bf16x8*)(op0 + (size_t)r * C_ + c) = *(const bf16x8*)(vp0 + (size_t)r * D_ + c);
    }
    return;
  }

  const ushort_t* qp = q + (size_t)bh * L_ * D_;
  const ushort_t* kp = k + (size_t)bh * L_ * D_ + (size_t)kvb * D_;
  const ushort_t* vp = vT + (size_t)bh * D_ * L_ + kvb;

  bf16x8 qf[8];
  #pragma unroll
  for (int dt = 0; dt < 8; ++dt)
    qf[dt] = *(const bf16x8*)(qp + (size_t)(qw + lo32) * D_ + dt * 16 + hi2 * 8);

  const u64* mp = (h == 1) ? a1p : (h == 2) ? a2p : (h == 3) ? d2p : d3p;
  bool full = (h == 5);
  const u64* mrow = mp + ((size_t)b * L_ + qw + lo32) * 16 + half * 8;

  float m_run = NEGINF, l_run = 0.f;
  f32x16 acc[4];
  #pragma unroll
  for (int dt = 0; dt < 4; ++dt)
    #pragma unroll
    for (int r = 0; r < 16; ++r) acc[dt][r] = 0.f;

  // stage one 32-col K/V chunk: 2 global_load_lds per thread (512 threads)
  auto stage = [&](int buf, int ch) {
    int kc0 = ch * 32;
    {
      int row = t >> 4, c16 = t & 15;      // K: 32 rows x 16 slots
      int sc = c16 ^ (row & 15);
      __builtin_amdgcn_global_load_lds(
          (const AS1 void*)(kp + (size_t)(kc0 + row) * D_ + sc * 8),
          (AS3 void*)&Ks[buf][(size_t)t * 8], 16, 0, 0);
    }
    {
      int row = t >> 2, c16 = t & 3;       // V: 128 rows x 4 slots
      int sc = c16 ^ (row & 3);
      __builtin_amdgcn_global_load_lds(
          (const AS1 void*)(vp + (size_t)row * L_ + kc0 + sc * 8),
          (AS3 void*)&Vs[buf][(size_t)t * 8], 16, 0, 0);
    }
  };

  stage(0, 0);
  u64 mw_cur = full ? 0ULL : mrow[0];
  u64 mw_nxt = 0ULL;
  __syncthreads();

  for (int ch = 0; ch < 16; ++ch) {
    int cur = ch & 1;
    if (ch < 15) stage(cur ^ 1, ch + 1);        // prefetch next chunk
    if (!full && (ch & 1) == 0 && (ch >> 1) + 1 < 8)
      mw_nxt = mrow[(ch >> 1) + 1];

    const ushort_t* ks = &Ks[cur][0];
    const ushort_t* vs = &Vs[cur][0];
    uint_t mbits = full ? 0xffffffffu : (uint_t)(mw_cur >> ((ch & 1) * 32));

    // S^T: sacc[r] = S[q=lo32][kvb + ch*32 + crow(r,hi2)]
    f32x16 sacc;
    #pragma unroll
    for (int r = 0; r < 16; ++r) sacc[r] = 0.f;
    __builtin_amdgcn_s_setprio(1);
    #pragma unroll
    for (int dt = 0; dt < 8; ++dt) {
      int c16 = (dt * 2 + hi2) ^ (lo32 & 15);
      bf16x8 kf = *(const bf16x8*)&ks[lo32 * 128 + c16 * 8];
      sacc = __builtin_amdgcn_mfma_f32_32x32x16_bf16(kf, qf[dt], sacc, 0, 0, 0);
    }
    __builtin_amdgcn_s_setprio(0);

    float sv[16];
    #pragma unroll
    for (int r = 0; r < 16; ++r) {
      int shift = (r & 3) + 8 * (r >> 2) + hi2 * 4;
      sv[r] = ((mbits >> shift) & 1u) ? sacc[r] : NEGINF;
    }

    // in-lane max tree + 1 cross-lane
    float a8[8];
    #pragma unroll
    for (int j = 0; j < 8; ++j) a8[j] = fmaxf(sv[2 * j], sv[2 * j + 1]);
    #pragma unroll
    for (int j = 0; j < 4; ++j) a8[j] = fmaxf(a8[j], a8[j + 4]);
    float pmax = fmaxf(fmaxf(a8[0], a8[1]), fmaxf(a8[2], a8[3]));
    pmax = fmaxf(pmax, __shfl_xor(pmax, 32));

    // defer-max (T13)
    if (__any(pmax > m_run + THR_)) {
      float mn = fmaxf(m_run, pmax);
      float corr = __expf(m_run - mn);
      l_run *= corr;
      m_run = mn;
      float cT[16];
      #pragma unroll
      for (int r = 0; r < 16; ++r)
        cT[r] = __shfl(corr, (r & 3) + 8 * (r >> 2) + hi2 * 4);
      #pragma unroll
      for (int dt = 0; dt < 4; ++dt)
        #pragma unroll
        for (int r = 0; r < 16; ++r) acc[dt][r] *= cT[r];
    }

    // P = exp(S - m_run); row-sum
    float p[16];
    #pragma unroll
    for (int r = 0; r < 16; ++r) p[r] = __expf(sv[r] - m_run);
    float s8[8];
    #pragma unroll
    for (int j = 0; j < 8; ++j) s8[j] = p[2 * j] + p[2 * j + 1];
    #pragma unroll
    for (int j = 0; j < 4; ++j) s8[j] = s8[j] + s8[j + 4];
    float rs = (s8[0] + s8[1]) + (s8[2] + s8[3]);
    rs += __shfl_xor(rs, 32);
    l_run += rs;

    // pack P; half-swap to build PV A-frags (R6/R8-verified)
    uint_t ow[8];
    #pragma unroll
    for (int j = 0; j < 8; ++j)
      ow[j] = (uint_t)f2bf(p[2 * j]) | ((uint_t)f2bf(p[2 * j + 1]) << 16);
    uint_t pw[8];
    #pragma unroll
    for (int j = 0; j < 8; ++j) pw[j] = __shfl_xor(ow[j], 32);
    u32x4 pa0 = (u32x4){hi2 ? pw[2] : ow[0], hi2 ? pw[3] : ow[1],
                        hi2 ? ow[2] : pw[0], hi2 ? ow[3] : pw[1]};
    u32x4 pa1 = (u32x4){hi2 ? pw[6] : ow[4], hi2 ? pw[7] : ow[5],
                        hi2 ? ow[6] : pw[4], hi2 ? ow[7] : pw[5]};
    bf16x8 paf0 = __builtin_bit_cast(bf16x8, pa0);
    bf16x8 paf1 = __builtin_bit_cast(bf16x8, pa1);

    // PV: paf0 ~ kv 0..15, paf1 ~ kv 16..31 of the chunk
    __builtin_amdgcn_s_setprio(1);
    #pragma unroll
    for (int dt = 0; dt < 4; ++dt) {
      int vd = dt * 32 + lo32;
      int c16a = hi2 ^ (vd & 3);
      int c16b = (2 + hi2) ^ (vd & 3);
      bf16x8 vfa = *(const bf16x8*)&vs[vd * 32 + c16a * 8];
      bf16x8 vfb = *(const bf16x8*)&vs[vd * 32 + c16b * 8];
      acc[dt] = __builtin_amdgcn_mfma_f32_32x32x16_bf16(paf0, vfa, acc[dt], 0, 0, 0);
      acc[dt] = __builtin_amdgcn_mfma_f32_32x32x16_bf16(paf1, vfb, acc[dt], 0, 0, 0);
    }
    __builtin_amdgcn_s_setprio(0);
    if (ch & 1) mw_cur = mw_nxt;
    __syncthreads();
  }

  // epilogue: write partials. (m,l) per q-row (hi2==0 lanes); N unnormalized bf16.
  if (hi2 == 0) {
    size_t row = (size_t)bh * L_ + qw + lo32;
    float2 v2 = make_float2(m_run, l_run);
    *(float2*)(ml + ((size_t)half * BH_ * L_ + row) * 2) = v2;
  }
  ushort_t* np = half ? np1 : np0;
  #pragma unroll
  for (int dt = 0; dt < 4; ++dt)
    #pragma unroll
    for (int r = 0; r < 16; ++r) {
      int qrow = qw + (r & 3) + 8 * (r >> 2) + hi2 * 4;
      np[((size_t)bh * L_ + qrow) * D_ + dt * 32 + lo32] = f2bf(acc[dt][r]);
    }
}

// ------------------------------------------------- split-K combine
__global__ __launch_bounds__(256)
void combine(const ushort_t* __restrict__ np0, const ushort_t* __restrict__ np1,
             const float* __restrict__ ml, ushort_t* __restrict__ obf) {
  int bh = blockIdx.x;
  int b = bh / H_, h = bh - b * H_;
  if (h == 0) return;                       // eye head written directly
  int t = threadIdx.x;
  int qi = t >> 4, di = t & 15;             // 16 q-rows x 16 d-groups of 8
  int qq = blockIdx.y * 16 + qi;
  size_t row = (size_t)bh * L_ + qq;
  float2 ml1 = *(const float2*)(ml + row * 2);
  float2 ml2 = *(const float2*)(ml + ((size_t)BH_ * L_ + row) * 2);
  float M = fmaxf(ml1.x, ml2.x);
  float w1 = __expf(ml1.x - M), w2 = __expf(ml2.x - M);
  float inv = 1.f / (w1 * ml1.y + w2 * ml2.y);
  bf16x8 n1 = *(const bf16x8*)(np0 + row * D_ + di * 8);
  bf16x8 n2 = *(const bf16x8*)(np1 + row * D_ + di * 8);
  ushort_t o[8];
  #pragma unroll
  for (int j = 0; j < 8; ++j)
    o[j] = f2bf((w1 * bf2f((ushort_t)n1[j]) + w2 * bf2f((ushort_t)n2[j])) * inv);
  *(bf16x8*)(obf + ((size_t)b * L_ + qq) * C_ + h * D_ + di * 8) = *(bf16x8*)o;
}

// ---------------------------------------------------------------- launcher
extern "C" void kernel_launch(void* const* d_in, const int* in_sizes, int n_in,
                              void* d_out, int out_size, void* d_ws, size_t ws_size,
                              hipStream_t stream) {
  const float* x     = (const float*)d_in[0];
  const int*   adj   = (const int*)d_in[1];
  const int*   dist  = (const int*)d_in[2];
  const float* wqkv  = (const float*)d_in[3];
  const float* wproj = (const float*)d_in[4];
  float* out = (float*)d_out;
  char* ws = (char*)d_ws;

  const size_t SZ_X   = (size_t)B_ * L_ * C_ * 2;        // 12.6 MB (== SZ_QKV)
  const size_t SZ_WQ  = (size_t)3 * C_ * C_ * 2;
  const size_t SZ_WP  = (size_t)C_ * C_ * 2;
  const size_t SZ_QKV = (size_t)BH_ * L_ * D_ * 2;       // 12.6 MB
  const size_t SZ_MSK = (size_t)B_ * L_ * 16 * 8;        // 1 MB
  const size_t SZ_ML  = (size_t)2 * BH_ * L_ * 2 * 4;    // 0.79 MB
  size_t off = 0;
  ushort_t* xbf  = (ushort_t*)(ws + off); off += SZ_X;   // reused as np0 post-GEMM
  ushort_t* wqb  = (ushort_t*)(ws + off); off += SZ_WQ;
  ushort_t* wpb  = (ushort_t*)(ws + off); off += SZ_WP;
  ushort_t* qb   = (ushort_t*)(ws + off); off += SZ_QKV;
  ushort_t* kb   = (ushort_t*)(ws + off); off += SZ_QKV;
  ushort_t* vTb  = (ushort_t*)(ws + off); off += SZ_QKV;
  ushort_t* vb   = (ushort_t*)(ws + off); off += SZ_QKV;
  ushort_t* ob   = (ushort_t*)(ws + off); off += SZ_X;
  u64* a1p = (u64*)(ws + off); off += SZ_MSK;
  u64* a2p = (u64*)(ws + off); off += SZ_MSK;
  u64* d2p = (u64*)(ws + off); off += SZ_MSK;
  u64* d3p = (u64*)(ws + off); off += SZ_MSK;
  ushort_t* np1 = (ushort_t*)(ws + off); off += SZ_QKV;  // partial N half 1
  float*    mlb = (float*)(ws + off); off += SZ_ML;      // (m,l)[2][BH][L]
  ushort_t* np0 = xbf;                                   // partial N half 0
  (void)ws_size; (void)n_in; (void)in_sizes; (void)out_size;

  cvt_f32_bf16<<<(B_ * L_ * C_ / 8 + 255) / 256, 256, 0, stream>>>(x, xbf, B_ * L_ * C_ / 8);
  cvt_f32_bf16<<<(3 * C_ * C_ / 8 + 255) / 256, 256, 0, stream>>>(wqkv, wqb, 3 * C_ * C_ / 8);
  cvt_f32_bf16<<<(C_ * C_ / 8 + 255) / 256, 256, 0, stream>>>(wproj, wpb, C_ * C_ / 8);
  pack_masks<<<dim3(L_, B_), 256, 0, stream>>>(adj, dist, a1p, d2p, d3p);
  hop2<<<B_ * L_ / 64, 64, 0, stream>>>(a1p, a2p);
  // qkv = x @ wqkv^T  (M=8192, N=2304, K=768), nwg=1152 (%8==0)
  gemm_bt<0><<<dim3(3 * C_ / 128, B_ * L_ / 128), 256, 0, stream>>>(
      xbf, wqb, 3 * C_, C_, qb, kb, vTb, vb, nullptr);
  // attention split-K=2: 8-wave blocks, 256 q-rows; grid (bh, qt, half)
  attn_kernel<<<dim3(BH_, L_ / 256, 2), 512, 0, stream>>>(
      qb, kb, vTb, vb, ob, np0, np1, mlb, a1p, a2p, d2p, d3p);
  combine<<<dim3(BH_, L_ / 16), 256, 0, stream>>>(np0, np1, mlb, ob);
  // out = O @ wproj^T  (M=8192, N=768, K=768), nwg=384 (%8==0)
  gemm_bt<1><<<dim3(C_ / 128, B_ * L_ / 128), 256, 0, stream>>>(
      ob, wpb, C_, C_, nullptr, nullptr, nullptr, nullptr, out);
}

// Round 12
// 183.584 us; speedup vs baseline: 1.5089x; 1.1097x over previous
//
#include <hip/hip_runtime.h>

typedef unsigned short ushort_t;
typedef unsigned int uint_t;
typedef unsigned long long u64;
typedef __attribute__((ext_vector_type(8))) short bf16x8;
typedef __attribute__((ext_vector_type(4))) float f32x4;
typedef __attribute__((ext_vector_type(16))) float f32x16;
typedef __attribute__((ext_vector_type(4))) uint_t u32x4;

#define B_ 8
#define L_ 1024
#define C_ 768
#define H_ 6
#define D_ 128
#define BH_ 48
#define NEGINF (-1e9f)
#define THR_ 8.0f

#define AS1 __attribute__((address_space(1)))
#define AS3 __attribute__((address_space(3)))

// round-to-nearest-even f32 -> bf16
__device__ __forceinline__ ushort_t f2bf(float f) {
  uint_t u = __builtin_bit_cast(uint_t, f);
  u += 0x7fffu + ((u >> 16) & 1u);
  return (ushort_t)(u >> 16);
}
__device__ __forceinline__ float bf2f(ushort_t s) {
  uint_t u = ((uint_t)s) << 16;
  return __builtin_bit_cast(float, u);
}

// ---------------------------------------------------------------- converts
__global__ void cvt_f32_bf16(const float* __restrict__ in, ushort_t* __restrict__ out, int n8) {
  int i = blockIdx.x * 256 + threadIdx.x;
  if (i >= n8) return;
  const float4* p = (const float4*)in + (size_t)i * 2;
  float4 a = p[0], b = p[1];
  uint4 r;
  r.x = (uint_t)f2bf(a.x) | ((uint_t)f2bf(a.y) << 16);
  r.y = (uint_t)f2bf(a.z) | ((uint_t)f2bf(a.w) << 16);
  r.z = (uint_t)f2bf(b.x) | ((uint_t)f2bf(b.y) << 16);
  r.w = (uint_t)f2bf(b.z) | ((uint_t)f2bf(b.w) << 16);
  ((uint4*)out)[i] = r;
}

// ------------------------------------------------- bit-pack a1 / d<=2 / d<=3
__global__ __launch_bounds__(256)
void pack_masks(const int* __restrict__ adj, const int* __restrict__ dist,
                u64* __restrict__ a1p, u64* __restrict__ d2p, u64* __restrict__ d3p) {
  int l = blockIdx.x, b = blockIdx.y, t = threadIdx.x;
  size_t base = ((size_t)b * L_ + l) * L_;
  size_t rb = ((size_t)b * L_ + l) * 16;
  #pragma unroll
  for (int it = 0; it < 4; ++it) {
    int c = it * 256 + t;
    int av = adj[base + c];
    int dv = dist[base + c];
    u64 m1 = __ballot((av > 0) || (c == l));
    u64 m2 = __ballot(dv <= 2);
    u64 m3 = __ballot(dv <= 3);
    if ((t & 63) == 0) {
      int w = it * 4 + (t >> 6);
      a1p[rb + w] = m1; d2p[rb + w] = m2; d3p[rb + w] = m3;
    }
  }
}

// ------------------------------------------------- 2-hop closure (bit OR)
__global__ __launch_bounds__(64)
void hop2(const u64* __restrict__ a1p, u64* __restrict__ a2p) {
  int tid = blockIdx.x * 64 + threadIdx.x;   // 0..8191 = (b,l)
  int b = tid >> 10;
  size_t rb = (size_t)tid * 16;
  u64 row[16], acc[16];
  #pragma unroll
  for (int j = 0; j < 16; ++j) { row[j] = a1p[rb + j]; acc[j] = 0ULL; }
  bool done = false;
  #pragma unroll
  for (int mw = 0; mw < 16; ++mw) {
    if (done) continue;
    u64 bits = row[mw];
    while (bits) {
      int tz = __builtin_ctzll(bits); bits &= bits - 1;
      const u64* src = a1p + (((size_t)b << 10) + (mw << 6) + tz) * 16;
      u64 band = ~0ULL;
      #pragma unroll
      for (int j = 0; j < 16; ++j) { acc[j] |= src[j]; band &= acc[j]; }
      if (band == ~0ULL) { done = true; break; }
    }
  }
  #pragma unroll
  for (int j = 0; j < 16; ++j) a2p[rb + j] = acc[j];
}

// ------------------------------------------------- bf16 GEMM  C = A @ B^T
// 128x128 tile, BK=64, T2 both-sides XOR swizzle, bijective XCD swizzle.
// EPI==0 epilogue is BLOCK-UNIFORM in sec (n-tiles 128-wide, 768%128==0):
//   sec0 -> q (scaled, coalesced), sec1 -> k (coalesced),
//   sec2 h==0 -> v row-major only, sec2 h!=0 -> vT via LDS transpose.
template<int EPI>
__global__ __launch_bounds__(256)
void gemm_bt(const ushort_t* __restrict__ A, const ushort_t* __restrict__ Bm,
             int N, int K,
             ushort_t* __restrict__ qo, ushort_t* __restrict__ ko,
             ushort_t* __restrict__ vTo, ushort_t* __restrict__ vo,
             float* __restrict__ fo) {
  __shared__ __align__(16) ushort_t As[128 * 64];   // 16 KB
  __shared__ __align__(16) ushort_t Bs[128 * 64];   // 16 KB
  int t = threadIdx.x;
  int lane = t & 63, lo = lane & 15, hi = lane >> 4;
  int wv = t >> 6, wm = wv >> 1, wn = wv & 1;

  int gx = gridDim.x;
  int nwg = gx * gridDim.y;
  int orig = blockIdx.y * gx + blockIdx.x;
  int cpx = nwg >> 3;
  int wg = (orig & 7) * cpx + (orig >> 3);
  int n0 = (wg % gx) * 128;
  int m0 = (wg / gx) * 128;

  f32x4 acc[4][4];
  #pragma unroll
  for (int mi = 0; mi < 4; ++mi)
    #pragma unroll
    for (int ni = 0; ni < 4; ++ni) acc[mi][ni] = (f32x4){0.f, 0.f, 0.f, 0.f};

  for (int kt = 0; kt < K; kt += 64) {
    #pragma unroll
    for (int i = 0; i < 4; ++i) {
      int u = i * 256 + t;                 // 0..1023
      int row = u >> 3, c16 = u & 7;
      int sc = c16 ^ (row & 7);
      __builtin_amdgcn_global_load_lds(
          (const AS1 void*)(A + ((size_t)(m0 + row) * K + kt + sc * 8)),
          (AS3 void*)&As[(size_t)u * 8], 16, 0, 0);
      __builtin_amdgcn_global_load_lds(
          (const AS1 void*)(Bm + ((size_t)(n0 + row) * K + kt + sc * 8)),
          (AS3 void*)&Bs[(size_t)u * 8], 16, 0, 0);
    }
    __syncthreads();
    #pragma unroll
    for (int kks = 0; kks < 2; ++kks) {
      bf16x8 af[4], bfr[4];
      #pragma unroll
      for (int mi = 0; mi < 4; ++mi) {
        int r = wm * 64 + mi * 16 + lo;
        af[mi] = *(const bf16x8*)&As[r * 64 + (((kks * 4 + hi) ^ (r & 7)) * 8)];
      }
      #pragma unroll
      for (int ni = 0; ni < 4; ++ni) {
        int r = wn * 64 + ni * 16 + lo;
        bfr[ni] = *(const bf16x8*)&Bs[r * 64 + (((kks * 4 + hi) ^ (r & 7)) * 8)];
      }
      #pragma unroll
      for (int mi = 0; mi < 4; ++mi)
        #pragma unroll
        for (int ni = 0; ni < 4; ++ni)
          acc[mi][ni] = __builtin_amdgcn_mfma_f32_16x16x32_bf16(af[mi], bfr[ni], acc[mi][ni], 0, 0, 0);
    }
    __syncthreads();
  }

  // epilogue. D layout: col = lane&15, row = (lane>>4)*4 + j  [m89-verified]
  if (EPI == 1) {
    #pragma unroll
    for (int mi = 0; mi < 4; ++mi) {
      int rbase = m0 + wm * 64 + mi * 16 + hi * 4;
      #pragma unroll
      for (int ni = 0; ni < 4; ++ni) {
        int c = n0 + wn * 64 + ni * 16 + lo;
        f32x4 v = acc[mi][ni];
        #pragma unroll
        for (int j = 0; j < 4; ++j)
          fo[(size_t)(rbase + j) * N + c] = v[j];
      }
    }
    return;
  }
  // EPI == 0: block-uniform section
  int sec = n0 / 768;
  if (sec < 2) {
    #pragma unroll
    for (int mi = 0; mi < 4; ++mi) {
      int rbase = m0 + wm * 64 + mi * 16 + hi * 4;
      #pragma unroll
      for (int ni = 0; ni < 4; ++ni) {
        int cc = n0 - sec * 768 + wn * 64 + ni * 16 + lo;
        int hh = cc >> 7, dd = cc & 127;
        f32x4 v = acc[mi][ni];
        #pragma unroll
        for (int j = 0; j < 4; ++j) {
          int r = rbase + j;
          int b = r >> 10, l = r & 1023;
          size_t bh = (size_t)(b * H_ + hh);
          if (sec == 0) qo[(bh * L_ + l) * D_ + dd] = f2bf(v[j] * 0.08838834764831845f);
          else          ko[(bh * L_ + l) * D_ + dd] = f2bf(v[j]);
        }
      }
    }
    return;
  }
  // sec == 2: V third. h is block-uniform.
  int hh = (n0 - 1536) >> 7;
  int b = m0 >> 10, l0 = m0 & 1023;
  size_t bh = (size_t)(b * H_ + hh);
  if (hh == 0) {
    // eye head: only row-major v needed (coalesced 2B stores)
    #pragma unroll
    for (int mi = 0; mi < 4; ++mi) {
      int lb = wm * 64 + mi * 16 + hi * 4;
      #pragma unroll
      for (int ni = 0; ni < 4; ++ni) {
        int dd = wn * 64 + ni * 16 + lo;
        f32x4 v = acc[mi][ni];
        #pragma unroll
        for (int j = 0; j < 4; ++j)
          vo[(bh * L_ + l0 + lb + j) * D_ + dd] = f2bf(v[j]);
      }
    }
    return;
  }
  // h != 0: only vT needed. LDS transpose (As/Bs free past the final barrier).
  // Element (dd, l): byte = (dd&63)*256 + l*2, XOR (dd&7)<<4 (bits 4-6 only,
  // consistent between 2B scatter and 16B chunk read -- rule #21).
  #pragma unroll
  for (int mi = 0; mi < 4; ++mi) {
    int lb = wm * 64 + mi * 16 + hi * 4;
    #pragma unroll
    for (int ni = 0; ni < 4; ++ni) {
      int dd = wn * 64 + ni * 16 + lo;
      ushort_t* base = (dd < 64) ? As : Bs;
      f32x4 v = acc[mi][ni];
      #pragma unroll
      for (int j = 0; j < 4; ++j) {
        int byte = (((dd & 63) * 256 + (lb + j) * 2)) ^ ((dd & 7) << 4);
        *(ushort_t*)((char*)base + byte) = f2bf(v[j]);
      }
    }
  }
  __syncthreads();
  #pragma unroll
  for (int i = 0; i < 8; ++i) {
    int u = i * 256 + t;            // 2048 chunks: dd 0..127 x 16 16B-chunks
    int ddl = u >> 4, c16 = u & 15;
    const ushort_t* base = (ddl < 64) ? As : Bs;
    int byte = (((ddl & 63) * 256 + c16 * 16)) ^ ((ddl & 7) << 4);
    bf16x8 val = *(const bf16x8*)((const char*)base + byte);
    *(bf16x8*)(vTo + (bh * D_ + ddl) * L_ + l0 + c16 * 8) = val;
  }
}

// ------------------------------------------------- flash attention, split-K=2
// 8 waves / block, 256 q-rows (32/wave); kv half per blockIdx.z; KVBLK=32.
__global__ __launch_bounds__(512)
void attn_kernel(const ushort_t* __restrict__ q, const ushort_t* __restrict__ k,
                 const ushort_t* __restrict__ vT, const ushort_t* __restrict__ v,
                 ushort_t* __restrict__ obf,
                 ushort_t* __restrict__ np0, ushort_t* __restrict__ np1,
                 float* __restrict__ ml,
                 const u64* __restrict__ a1p, const u64* __restrict__ a2p,
                 const u64* __restrict__ d2p, const u64* __restrict__ d3p) {
  __shared__ __align__(16) ushort_t Ks[2][32 * 128];   // [krow][d]  8 KB x2
  __shared__ __align__(16) ushort_t Vs[2][128 * 32];   // [d][kcol]  8 KB x2
  int t = threadIdx.x;
  int lane = t & 63, lo32 = lane & 31, hi2 = (lane >> 5) & 1, wv = t >> 6;
  int bh = blockIdx.x, qt = blockIdx.y, half = blockIdx.z;
  int b = bh / H_, h = bh - b * H_;
  int qbase = qt * 256;
  int qw = qbase + wv * 32;
  int kvb = half * 512;

  if (h == 0) {
    if (half) return;
    // eye mask: out = v[l]  (h*D_ == 0 in output)
    const ushort_t* vp0 = v + ((size_t)bh * L_ + qbase) * D_;
    ushort_t* op0 = obf + ((size_t)b * L_ + qbase) * C_;
    #pragma unroll
    for (int it = 0; it < 8; ++it) {
      int u = it * 512 + t;
      int r = u >> 4, c = (u & 15) * 8;
      *(bf16x8*)(op0 + (size_t)r * C_ + c) = *(const bf16x8*)(vp0 + (size_t)r * D_ + c);
    }
    return;
  }

  const ushort_t* qp = q + (size_t)bh * L_ * D_;
  const ushort_t* kp = k + (size_t)bh * L_ * D_ + (size_t)kvb * D_;
  const ushort_t* vp = vT + (size_t)bh * D_ * L_ + kvb;

  bf16x8 qf[8];
  #pragma unroll
  for (int dt = 0; dt < 8; ++dt)
    qf[dt] = *(const bf16x8*)(qp + (size_t)(qw + lo32) * D_ + dt * 16 + hi2 * 8);

  const u64* mp = (h == 1) ? a1p : (h == 2) ? a2p : (h == 3) ? d2p : d3p;
  bool full = (h == 5);
  const u64* mrow = mp + ((size_t)b * L_ + qw + lo32) * 16 + half * 8;

  float m_run = NEGINF, l_run = 0.f;
  f32x16 acc[4];
  #pragma unroll
  for (int dt = 0; dt < 4; ++dt)
    #pragma unroll
    for (int r = 0; r < 16; ++r) acc[dt][r] = 0.f;

  // stage one 32-col K/V chunk: 2 global_load_lds per thread (512 threads)
  auto stage = [&](int buf, int ch) {
    int kc0 = ch * 32;
    {
      int row = t >> 4, c16 = t & 15;      // K: 32 rows x 16 slots
      int sc = c16 ^ (row & 15);
      __builtin_amdgcn_global_load_lds(
          (const AS1 void*)(kp + (size_t)(kc0 + row) * D_ + sc * 8),
          (AS3 void*)&Ks[buf][(size_t)t * 8], 16, 0, 0);
    }
    {
      int row = t >> 2, c16 = t & 3;       // V: 128 rows x 4 slots
      int sc = c16 ^ (row & 3);
      __builtin_amdgcn_global_load_lds(
          (const AS1 void*)(vp + (size_t)row * L_ + kc0 + sc * 8),
          (AS3 void*)&Vs[buf][(size_t)t * 8], 16, 0, 0);
    }
  };

  stage(0, 0);
  u64 mw_cur = full ? 0ULL : mrow[0];
  u64 mw_nxt = 0ULL;
  __syncthreads();

  for (int ch = 0; ch < 16; ++ch) {
    int cur = ch & 1;
    if (ch < 15) stage(cur ^ 1, ch + 1);        // prefetch next chunk
    if (!full && (ch & 1) == 0 && (ch >> 1) + 1 < 8)
      mw_nxt = mrow[(ch >> 1) + 1];

    const ushort_t* ks = &Ks[cur][0];
    const ushort_t* vs = &Vs[cur][0];
    uint_t mbits = full ? 0xffffffffu : (uint_t)(mw_cur >> ((ch & 1) * 32));

    // S^T: sacc[r] = S[q=lo32][kvb + ch*32 + crow(r,hi2)]
    f32x16 sacc;
    #pragma unroll
    for (int r = 0; r < 16; ++r) sacc[r] = 0.f;
    __builtin_amdgcn_s_setprio(1);
    #pragma unroll
    for (int dt = 0; dt < 8; ++dt) {
      int c16 = (dt * 2 + hi2) ^ (lo32 & 15);
      bf16x8 kf = *(const bf16x8*)&ks[lo32 * 128 + c16 * 8];
      sacc = __builtin_amdgcn_mfma_f32_32x32x16_bf16(kf, qf[dt], sacc, 0, 0, 0);
    }
    __builtin_amdgcn_s_setprio(0);

    float sv[16];
    #pragma unroll
    for (int r = 0; r < 16; ++r) {
      int shift = (r & 3) + 8 * (r >> 2) + hi2 * 4;
      sv[r] = ((mbits >> shift) & 1u) ? sacc[r] : NEGINF;
    }

    // in-lane max tree + 1 cross-lane
    float a8[8];
    #pragma unroll
    for (int j = 0; j < 8; ++j) a8[j] = fmaxf(sv[2 * j], sv[2 * j + 1]);
    #pragma unroll
    for (int j = 0; j < 4; ++j) a8[j] = fmaxf(a8[j], a8[j + 4]);
    float pmax = fmaxf(fmaxf(a8[0], a8[1]), fmaxf(a8[2], a8[3]));
    pmax = fmaxf(pmax, __shfl_xor(pmax, 32));

    // defer-max (T13)
    if (__any(pmax > m_run + THR_)) {
      float mn = fmaxf(m_run, pmax);
      float corr = __expf(m_run - mn);
      l_run *= corr;
      m_run = mn;
      float cT[16];
      #pragma unroll
      for (int r = 0; r < 16; ++r)
        cT[r] = __shfl(corr, (r & 3) + 8 * (r >> 2) + hi2 * 4);
      #pragma unroll
      for (int dt = 0; dt < 4; ++dt)
        #pragma unroll
        for (int r = 0; r < 16; ++r) acc[dt][r] *= cT[r];
    }

    // P = exp(S - m_run); row-sum
    float p[16];
    #pragma unroll
    for (int r = 0; r < 16; ++r) p[r] = __expf(sv[r] - m_run);
    float s8[8];
    #pragma unroll
    for (int j = 0; j < 8; ++j) s8[j] = p[2 * j] + p[2 * j + 1];
    #pragma unroll
    for (int j = 0; j < 4; ++j) s8[j] = s8[j] + s8[j + 4];
    float rs = (s8[0] + s8[1]) + (s8[2] + s8[3]);
    rs += __shfl_xor(rs, 32);
    l_run += rs;

    // pack P; half-swap to build PV A-frags (R6/R8-verified)
    uint_t ow[8];
    #pragma unroll
    for (int j = 0; j < 8; ++j)
      ow[j] = (uint_t)f2bf(p[2 * j]) | ((uint_t)f2bf(p[2 * j + 1]) << 16);
    uint_t pw[8];
    #pragma unroll
    for (int j = 0; j < 8; ++j) pw[j] = __shfl_xor(ow[j], 32);
    u32x4 pa0 = (u32x4){hi2 ? pw[2] : ow[0], hi2 ? pw[3] : ow[1],
                        hi2 ? ow[2] : pw[0], hi2 ? ow[3] : pw[1]};
    u32x4 pa1 = (u32x4){hi2 ? pw[6] : ow[4], hi2 ? pw[7] : ow[5],
                        hi2 ? ow[6] : pw[4], hi2 ? ow[7] : pw[5]};
    bf16x8 paf0 = __builtin_bit_cast(bf16x8, pa0);
    bf16x8 paf1 = __builtin_bit_cast(bf16x8, pa1);

    // PV: paf0 ~ kv 0..15, paf1 ~ kv 16..31 of the chunk
    __builtin_amdgcn_s_setprio(1);
    #pragma unroll
    for (int dt = 0; dt < 4; ++dt) {
      int vd = dt * 32 + lo32;
      int c16a = hi2 ^ (vd & 3);
      int c16b = (2 + hi2) ^ (vd & 3);
      bf16x8 vfa = *(const bf16x8*)&vs[vd * 32 + c16a * 8];
      bf16x8 vfb = *(const bf16x8*)&vs[vd * 32 + c16b * 8];
      acc[dt] = __builtin_amdgcn_mfma_f32_32x32x16_bf16(paf0, vfa, acc[dt], 0, 0, 0);
      acc[dt] = __builtin_amdgcn_mfma_f32_32x32x16_bf16(paf1, vfb, acc[dt], 0, 0, 0);
    }
    __builtin_amdgcn_s_setprio(0);
    if (ch & 1) mw_cur = mw_nxt;
    __syncthreads();
  }

  // epilogue: write partials. (m,l) per q-row (hi2==0 lanes); N unnormalized bf16.
  if (hi2 == 0) {
    size_t row = (size_t)bh * L_ + qw + lo32;
    float2 v2 = make_float2(m_run, l_run);
    *(float2*)(ml + ((size_t)half * BH_ * L_ + row) * 2) = v2;
  }
  ushort_t* np = half ? np1 : np0;
  #pragma unroll
  for (int dt = 0; dt < 4; ++dt)
    #pragma unroll
    for (int r = 0; r < 16; ++r) {
      int qrow = qw + (r & 3) + 8 * (r >> 2) + hi2 * 4;
      np[((size_t)bh * L_ + qrow) * D_ + dt * 32 + lo32] = f2bf(acc[dt][r]);
    }
}

// ------------------------------------------------- split-K combine
__global__ __launch_bounds__(256)
void combine(const ushort_t* __restrict__ np0, const ushort_t* __restrict__ np1,
             const float* __restrict__ ml, ushort_t* __restrict__ obf) {
  int bh = blockIdx.x;
  int b = bh / H_, h = bh - b * H_;
  if (h == 0) return;                       // eye head written directly
  int t = threadIdx.x;
  int qi = t >> 4, di = t & 15;             // 16 q-rows x 16 d-groups of 8
  int qq = blockIdx.y * 16 + qi;
  size_t row = (size_t)bh * L_ + qq;
  float2 ml1 = *(const float2*)(ml + row * 2);
  float2 ml2 = *(const float2*)(ml + ((size_t)BH_ * L_ + row) * 2);
  float M = fmaxf(ml1.x, ml2.x);
  float w1 = __expf(ml1.x - M), w2 = __expf(ml2.x - M);
  float inv = 1.f / (w1 * ml1.y + w2 * ml2.y);
  bf16x8 n1 = *(const bf16x8*)(np0 + row * D_ + di * 8);
  bf16x8 n2 = *(const bf16x8*)(np1 + row * D_ + di * 8);
  ushort_t o[8];
  #pragma unroll
  for (int j = 0; j < 8; ++j)
    o[j] = f2bf((w1 * bf2f((ushort_t)n1[j]) + w2 * bf2f((ushort_t)n2[j])) * inv);
  *(bf16x8*)(obf + ((size_t)b * L_ + qq) * C_ + h * D_ + di * 8) = *(bf16x8*)o;
}

// ---------------------------------------------------------------- launcher
extern "C" void kernel_launch(void* const* d_in, const int* in_sizes, int n_in,
                              void* d_out, int out_size, void* d_ws, size_t ws_size,
                              hipStream_t stream) {
  const float* x     = (const float*)d_in[0];
  const int*   adj   = (const int*)d_in[1];
  const int*   dist  = (const int*)d_in[2];
  const float* wqkv  = (const float*)d_in[3];
  const float* wproj = (const float*)d_in[4];
  float* out = (float*)d_out;
  char* ws = (char*)d_ws;

  const size_t SZ_X   = (size_t)B_ * L_ * C_ * 2;        // 12.6 MB (== SZ_QKV)
  const size_t SZ_WQ  = (size_t)3 * C_ * C_ * 2;
  const size_t SZ_WP  = (size_t)C_ * C_ * 2;
  const size_t SZ_QKV = (size_t)BH_ * L_ * D_ * 2;       // 12.6 MB
  const size_t SZ_MSK = (size_t)B_ * L_ * 16 * 8;        // 1 MB
  const size_t SZ_ML  = (size_t)2 * BH_ * L_ * 2 * 4;    // 0.79 MB
  size_t off = 0;
  ushort_t* xbf  = (ushort_t*)(ws + off); off += SZ_X;   // reused as np0 post-GEMM
  ushort_t* wqb  = (ushort_t*)(ws + off); off += SZ_WQ;
  ushort_t* wpb  = (ushort_t*)(ws + off); off += SZ_WP;
  ushort_t* qb   = (ushort_t*)(ws + off); off += SZ_QKV;
  ushort_t* kb   = (ushort_t*)(ws + off); off += SZ_QKV;
  ushort_t* vTb  = (ushort_t*)(ws + off); off += SZ_QKV;
  ushort_t* vb   = (ushort_t*)(ws + off); off += SZ_QKV;
  ushort_t* ob   = (ushort_t*)(ws + off); off += SZ_X;
  u64* a1p = (u64*)(ws + off); off += SZ_MSK;
  u64* a2p = (u64*)(ws + off); off += SZ_MSK;
  u64* d2p = (u64*)(ws + off); off += SZ_MSK;
  u64* d3p = (u64*)(ws + off); off += SZ_MSK;
  ushort_t* np1 = (ushort_t*)(ws + off); off += SZ_QKV;  // partial N half 1
  float*    mlb = (float*)(ws + off); off += SZ_ML;      // (m,l)[2][BH][L]
  ushort_t* np0 = xbf;                                   // partial N half 0
  (void)ws_size; (void)n_in; (void)in_sizes; (void)out_size;

  cvt_f32_bf16<<<(B_ * L_ * C_ / 8 + 255) / 256, 256, 0, stream>>>(x, xbf, B_ * L_ * C_ / 8);
  cvt_f32_bf16<<<(3 * C_ * C_ / 8 + 255) / 256, 256, 0, stream>>>(wqkv, wqb, 3 * C_ * C_ / 8);
  cvt_f32_bf16<<<(C_ * C_ / 8 + 255) / 256, 256, 0, stream>>>(wproj, wpb, C_ * C_ / 8);
  pack_masks<<<dim3(L_, B_), 256, 0, stream>>>(adj, dist, a1p, d2p, d3p);
  hop2<<<B_ * L_ / 64, 64, 0, stream>>>(a1p, a2p);
  // qkv = x @ wqkv^T  (M=8192, N=2304, K=768), nwg=1152 (%8==0)
  gemm_bt<0><<<dim3(3 * C_ / 128, B_ * L_ / 128), 256, 0, stream>>>(
      xbf, wqb, 3 * C_, C_, qb, kb, vTb, vb, nullptr);
  // attention split-K=2: 8-wave blocks, 256 q-rows; grid (bh, qt, half)
  attn_kernel<<<dim3(BH_, L_ / 256, 2), 512, 0, stream>>>(
      qb, kb, vTb, vb, ob, np0, np1, mlb, a1p, a2p, d2p, d3p);
  combine<<<dim3(BH_, L_ / 16), 256, 0, stream>>>(np0, np1, mlb, ob);
  // out = O @ wproj^T  (M=8192, N=768, K=768), nwg=384 (%8==0)
  gemm_bt<1><<<dim3(C_ / 128, B_ * L_ / 128), 256, 0, stream>>>(
      ob, wpb, C_, C_, nullptr, nullptr, nullptr, nullptr, out);
}

// Round 13
// 179.937 us; speedup vs baseline: 1.5394x; 1.0203x over previous
//
#include <hip/hip_runtime.h>

typedef unsigned short ushort_t;
typedef unsigned int uint_t;
typedef unsigned long long u64;
typedef __attribute__((ext_vector_type(8))) short bf16x8;
typedef __attribute__((ext_vector_type(4))) float f32x4;
typedef __attribute__((ext_vector_type(16))) float f32x16;
typedef __attribute__((ext_vector_type(4))) uint_t u32x4;

#define B_ 8
#define L_ 1024
#define C_ 768
#define H_ 6
#define D_ 128
#define BH_ 48
#define NEGINF (-1e9f)
#define THR_ 8.0f

#define AS1 __attribute__((address_space(1)))
#define AS3 __attribute__((address_space(3)))

// round-to-nearest-even f32 -> bf16
__device__ __forceinline__ ushort_t f2bf(float f) {
  uint_t u = __builtin_bit_cast(uint_t, f);
  u += 0x7fffu + ((u >> 16) & 1u);
  return (ushort_t)(u >> 16);
}
__device__ __forceinline__ float bf2f(ushort_t s) {
  uint_t u = ((uint_t)s) << 16;
  return __builtin_bit_cast(float, u);
}

// ---------------------------------------------------------------- converts
__global__ void cvt_f32_bf16(const float* __restrict__ in, ushort_t* __restrict__ out, int n8) {
  int i = blockIdx.x * 256 + threadIdx.x;
  if (i >= n8) return;
  const float4* p = (const float4*)in + (size_t)i * 2;
  float4 a = p[0], b = p[1];
  uint4 r;
  r.x = (uint_t)f2bf(a.x) | ((uint_t)f2bf(a.y) << 16);
  r.y = (uint_t)f2bf(a.z) | ((uint_t)f2bf(a.w) << 16);
  r.z = (uint_t)f2bf(b.x) | ((uint_t)f2bf(b.y) << 16);
  r.w = (uint_t)f2bf(b.z) | ((uint_t)f2bf(b.w) << 16);
  ((uint4*)out)[i] = r;
}

// ------------------------------------------------- bit-pack a1 / d<=2 / d<=3
__global__ __launch_bounds__(256)
void pack_masks(const int* __restrict__ adj, const int* __restrict__ dist,
                u64* __restrict__ a1p, u64* __restrict__ d2p, u64* __restrict__ d3p) {
  int l = blockIdx.x, b = blockIdx.y, t = threadIdx.x;
  size_t base = ((size_t)b * L_ + l) * L_;
  size_t rb = ((size_t)b * L_ + l) * 16;
  #pragma unroll
  for (int it = 0; it < 4; ++it) {
    int c = it * 256 + t;
    int av = adj[base + c];
    int dv = dist[base + c];
    u64 m1 = __ballot((av > 0) || (c == l));
    u64 m2 = __ballot(dv <= 2);
    u64 m3 = __ballot(dv <= 3);
    if ((t & 63) == 0) {
      int w = it * 4 + (t >> 6);
      a1p[rb + w] = m1; d2p[rb + w] = m2; d3p[rb + w] = m3;
    }
  }
}

// ------------------------------------------------- 2-hop closure (bit OR)
__global__ __launch_bounds__(64)
void hop2(const u64* __restrict__ a1p, u64* __restrict__ a2p) {
  int tid = blockIdx.x * 64 + threadIdx.x;   // 0..8191 = (b,l)
  int b = tid >> 10;
  size_t rb = (size_t)tid * 16;
  u64 row[16], acc[16];
  #pragma unroll
  for (int j = 0; j < 16; ++j) { row[j] = a1p[rb + j]; acc[j] = 0ULL; }
  bool done = false;
  #pragma unroll
  for (int mw = 0; mw < 16; ++mw) {
    if (done) continue;
    u64 bits = row[mw];
    while (bits) {
      int tz = __builtin_ctzll(bits); bits &= bits - 1;
      const u64* src = a1p + (((size_t)b << 10) + (mw << 6) + tz) * 16;
      u64 band = ~0ULL;
      #pragma unroll
      for (int j = 0; j < 16; ++j) { acc[j] |= src[j]; band &= acc[j]; }
      if (band == ~0ULL) { done = true; break; }
    }
  }
  #pragma unroll
  for (int j = 0; j < 16; ++j) a2p[rb + j] = acc[j];
}

// ------------------------------------------------- bf16 GEMM  C = A @ B^T
// 128x128 tile, BK=64, T2 both-sides XOR swizzle, bijective XCD swizzle.
// EPI==0 epilogue is BLOCK-UNIFORM in sec (n-tiles 128-wide, 768%128==0).
template<int EPI>
__global__ __launch_bounds__(256)
void gemm_bt(const ushort_t* __restrict__ A, const ushort_t* __restrict__ Bm,
             int N, int K,
             ushort_t* __restrict__ qo, ushort_t* __restrict__ ko,
             ushort_t* __restrict__ vTo, ushort_t* __restrict__ vo,
             float* __restrict__ fo) {
  __shared__ __align__(16) ushort_t As[128 * 64];   // 16 KB
  __shared__ __align__(16) ushort_t Bs[128 * 64];   // 16 KB
  int t = threadIdx.x;
  int lane = t & 63, lo = lane & 15, hi = lane >> 4;
  int wv = t >> 6, wm = wv >> 1, wn = wv & 1;

  int gx = gridDim.x;
  int nwg = gx * gridDim.y;
  int orig = blockIdx.y * gx + blockIdx.x;
  int cpx = nwg >> 3;
  int wg = (orig & 7) * cpx + (orig >> 3);
  int n0 = (wg % gx) * 128;
  int m0 = (wg / gx) * 128;

  f32x4 acc[4][4];
  #pragma unroll
  for (int mi = 0; mi < 4; ++mi)
    #pragma unroll
    for (int ni = 0; ni < 4; ++ni) acc[mi][ni] = (f32x4){0.f, 0.f, 0.f, 0.f};

  for (int kt = 0; kt < K; kt += 64) {
    #pragma unroll
    for (int i = 0; i < 4; ++i) {
      int u = i * 256 + t;                 // 0..1023
      int row = u >> 3, c16 = u & 7;
      int sc = c16 ^ (row & 7);
      __builtin_amdgcn_global_load_lds(
          (const AS1 void*)(A + ((size_t)(m0 + row) * K + kt + sc * 8)),
          (AS3 void*)&As[(size_t)u * 8], 16, 0, 0);
      __builtin_amdgcn_global_load_lds(
          (const AS1 void*)(Bm + ((size_t)(n0 + row) * K + kt + sc * 8)),
          (AS3 void*)&Bs[(size_t)u * 8], 16, 0, 0);
    }
    __syncthreads();
    #pragma unroll
    for (int kks = 0; kks < 2; ++kks) {
      bf16x8 af[4], bfr[4];
      #pragma unroll
      for (int mi = 0; mi < 4; ++mi) {
        int r = wm * 64 + mi * 16 + lo;
        af[mi] = *(const bf16x8*)&As[r * 64 + (((kks * 4 + hi) ^ (r & 7)) * 8)];
      }
      #pragma unroll
      for (int ni = 0; ni < 4; ++ni) {
        int r = wn * 64 + ni * 16 + lo;
        bfr[ni] = *(const bf16x8*)&Bs[r * 64 + (((kks * 4 + hi) ^ (r & 7)) * 8)];
      }
      #pragma unroll
      for (int mi = 0; mi < 4; ++mi)
        #pragma unroll
        for (int ni = 0; ni < 4; ++ni)
          acc[mi][ni] = __builtin_amdgcn_mfma_f32_16x16x32_bf16(af[mi], bfr[ni], acc[mi][ni], 0, 0, 0);
    }
    __syncthreads();
  }

  // epilogue. D layout: col = lane&15, row = (lane>>4)*4 + j  [m89-verified]
  if (EPI == 1) {
    #pragma unroll
    for (int mi = 0; mi < 4; ++mi) {
      int rbase = m0 + wm * 64 + mi * 16 + hi * 4;
      #pragma unroll
      for (int ni = 0; ni < 4; ++ni) {
        int c = n0 + wn * 64 + ni * 16 + lo;
        f32x4 v = acc[mi][ni];
        #pragma unroll
        for (int j = 0; j < 4; ++j)
          fo[(size_t)(rbase + j) * N + c] = v[j];
      }
    }
    return;
  }
  // EPI == 0: block-uniform section
  int sec = n0 / 768;
  if (sec < 2) {
    #pragma unroll
    for (int mi = 0; mi < 4; ++mi) {
      int rbase = m0 + wm * 64 + mi * 16 + hi * 4;
      #pragma unroll
      for (int ni = 0; ni < 4; ++ni) {
        int cc = n0 - sec * 768 + wn * 64 + ni * 16 + lo;
        int hh = cc >> 7, dd = cc & 127;
        f32x4 v = acc[mi][ni];
        #pragma unroll
        for (int j = 0; j < 4; ++j) {
          int r = rbase + j;
          int b = r >> 10, l = r & 1023;
          size_t bh = (size_t)(b * H_ + hh);
          if (sec == 0) qo[(bh * L_ + l) * D_ + dd] = f2bf(v[j] * 0.08838834764831845f);
          else          ko[(bh * L_ + l) * D_ + dd] = f2bf(v[j]);
        }
      }
    }
    return;
  }
  // sec == 2: V third. h is block-uniform.
  int hh = (n0 - 1536) >> 7;
  int b = m0 >> 10, l0 = m0 & 1023;
  size_t bh = (size_t)(b * H_ + hh);
  if (hh == 0) {
    // eye head: only row-major v needed
    #pragma unroll
    for (int mi = 0; mi < 4; ++mi) {
      int lb = wm * 64 + mi * 16 + hi * 4;
      #pragma unroll
      for (int ni = 0; ni < 4; ++ni) {
        int dd = wn * 64 + ni * 16 + lo;
        f32x4 v = acc[mi][ni];
        #pragma unroll
        for (int j = 0; j < 4; ++j)
          vo[(bh * L_ + l0 + lb + j) * D_ + dd] = f2bf(v[j]);
      }
    }
    return;
  }
  // h != 0: only vT needed. LDS transpose, XOR (dd&7)<<4 both sides.
  #pragma unroll
  for (int mi = 0; mi < 4; ++mi) {
    int lb = wm * 64 + mi * 16 + hi * 4;
    #pragma unroll
    for (int ni = 0; ni < 4; ++ni) {
      int dd = wn * 64 + ni * 16 + lo;
      ushort_t* base = (dd < 64) ? As : Bs;
      f32x4 v = acc[mi][ni];
      #pragma unroll
      for (int j = 0; j < 4; ++j) {
        int byte = (((dd & 63) * 256 + (lb + j) * 2)) ^ ((dd & 7) << 4);
        *(ushort_t*)((char*)base + byte) = f2bf(v[j]);
      }
    }
  }
  __syncthreads();
  #pragma unroll
  for (int i = 0; i < 8; ++i) {
    int u = i * 256 + t;            // 2048 chunks: dd 0..127 x 16 16B-chunks
    int ddl = u >> 4, c16 = u & 15;
    const ushort_t* base = (ddl < 64) ? As : Bs;
    int byte = (((ddl & 63) * 256 + c16 * 16)) ^ ((ddl & 7) << 4);
    bf16x8 val = *(const bf16x8*)((const char*)base + byte);
    *(bf16x8*)(vTo + (bh * D_ + ddl) * L_ + l0 + c16 * 8) = val;
  }
}

// ------------------------------------------------- flash attention, split-K=4
// 8 waves / block, 256 q-rows (32/wave); kv quarter per blockIdx.z; KVBLK=32,
// 8 chunks per block (128 KB staged). Partials: N (bf16) + (m,l) f32 per
// quarter; combine merges 4.
__global__ __launch_bounds__(512)
void attn_kernel(const ushort_t* __restrict__ q, const ushort_t* __restrict__ k,
                 const ushort_t* __restrict__ vT, const ushort_t* __restrict__ v,
                 ushort_t* __restrict__ obf,
                 ushort_t* __restrict__ np0, ushort_t* __restrict__ np1,
                 ushort_t* __restrict__ np2, ushort_t* __restrict__ np3,
                 float* __restrict__ ml,
                 const u64* __restrict__ a1p, const u64* __restrict__ a2p,
                 const u64* __restrict__ d2p, const u64* __restrict__ d3p) {
  __shared__ __align__(16) ushort_t Ks[2][32 * 128];   // [krow][d]  8 KB x2
  __shared__ __align__(16) ushort_t Vs[2][128 * 32];   // [d][kcol]  8 KB x2
  int t = threadIdx.x;
  int lane = t & 63, lo32 = lane & 31, hi2 = (lane >> 5) & 1, wv = t >> 6;
  int bh = blockIdx.x, qt = blockIdx.y, quar = blockIdx.z;
  int b = bh / H_, h = bh - b * H_;
  int qbase = qt * 256;
  int qw = qbase + wv * 32;
  int kvb = quar * 256;

  if (h == 0) {
    if (quar) return;
    // eye mask: out = v[l]  (h*D_ == 0 in output)
    const ushort_t* vp0 = v + ((size_t)bh * L_ + qbase) * D_;
    ushort_t* op0 = obf + ((size_t)b * L_ + qbase) * C_;
    #pragma unroll
    for (int it = 0; it < 8; ++it) {
      int u = it * 512 + t;
      int r = u >> 4, c = (u & 15) * 8;
      *(bf16x8*)(op0 + (size_t)r * C_ + c) = *(const bf16x8*)(vp0 + (size_t)r * D_ + c);
    }
    return;
  }

  const ushort_t* qp = q + (size_t)bh * L_ * D_;
  const ushort_t* kp = k + (size_t)bh * L_ * D_ + (size_t)kvb * D_;
  const ushort_t* vp = vT + (size_t)bh * D_ * L_ + kvb;

  bf16x8 qf[8];
  #pragma unroll
  for (int dt = 0; dt < 8; ++dt)
    qf[dt] = *(const bf16x8*)(qp + (size_t)(qw + lo32) * D_ + dt * 16 + hi2 * 8);

  const u64* mp = (h == 1) ? a1p : (h == 2) ? a2p : (h == 3) ? d2p : d3p;
  bool full = (h == 5);
  const u64* mrow = mp + ((size_t)b * L_ + qw + lo32) * 16 + quar * 4;

  float m_run = NEGINF, l_run = 0.f;
  f32x16 acc[4];
  #pragma unroll
  for (int dt = 0; dt < 4; ++dt)
    #pragma unroll
    for (int r = 0; r < 16; ++r) acc[dt][r] = 0.f;

  // stage one 32-col K/V chunk: 2 global_load_lds per thread (512 threads)
  auto stage = [&](int buf, int ch) {
    int kc0 = ch * 32;
    {
      int row = t >> 4, c16 = t & 15;      // K: 32 rows x 16 slots
      int sc = c16 ^ (row & 15);
      __builtin_amdgcn_global_load_lds(
          (const AS1 void*)(kp + (size_t)(kc0 + row) * D_ + sc * 8),
          (AS3 void*)&Ks[buf][(size_t)t * 8], 16, 0, 0);
    }
    {
      int row = t >> 2, c16 = t & 3;       // V: 128 rows x 4 slots
      int sc = c16 ^ (row & 3);
      __builtin_amdgcn_global_load_lds(
          (const AS1 void*)(vp + (size_t)row * L_ + kc0 + sc * 8),
          (AS3 void*)&Vs[buf][(size_t)t * 8], 16, 0, 0);
    }
  };

  stage(0, 0);
  u64 mw_cur = full ? 0ULL : mrow[0];
  u64 mw_nxt = 0ULL;
  __syncthreads();

  for (int ch = 0; ch < 8; ++ch) {
    int cur = ch & 1;
    if (ch < 7) stage(cur ^ 1, ch + 1);         // prefetch next chunk
    if (!full && (ch & 1) == 0 && (ch >> 1) + 1 < 4)
      mw_nxt = mrow[(ch >> 1) + 1];

    const ushort_t* ks = &Ks[cur][0];
    const ushort_t* vs = &Vs[cur][0];
    uint_t mbits = full ? 0xffffffffu : (uint_t)(mw_cur >> ((ch & 1) * 32));

    // S^T: sacc[r] = S[q=lo32][kvb + ch*32 + crow(r,hi2)]
    f32x16 sacc;
    #pragma unroll
    for (int r = 0; r < 16; ++r) sacc[r] = 0.f;
    __builtin_amdgcn_s_setprio(1);
    #pragma unroll
    for (int dt = 0; dt < 8; ++dt) {
      int c16 = (dt * 2 + hi2) ^ (lo32 & 15);
      bf16x8 kf = *(const bf16x8*)&ks[lo32 * 128 + c16 * 8];
      sacc = __builtin_amdgcn_mfma_f32_32x32x16_bf16(kf, qf[dt], sacc, 0, 0, 0);
    }
    __builtin_amdgcn_s_setprio(0);

    float sv[16];
    #pragma unroll
    for (int r = 0; r < 16; ++r) {
      int shift = (r & 3) + 8 * (r >> 2) + hi2 * 4;
      sv[r] = ((mbits >> shift) & 1u) ? sacc[r] : NEGINF;
    }

    // in-lane max tree + 1 cross-lane
    float a8[8];
    #pragma unroll
    for (int j = 0; j < 8; ++j) a8[j] = fmaxf(sv[2 * j], sv[2 * j + 1]);
    #pragma unroll
    for (int j = 0; j < 4; ++j) a8[j] = fmaxf(a8[j], a8[j + 4]);
    float pmax = fmaxf(fmaxf(a8[0], a8[1]), fmaxf(a8[2], a8[3]));
    pmax = fmaxf(pmax, __shfl_xor(pmax, 32));

    // defer-max (T13)
    if (__any(pmax > m_run + THR_)) {
      float mn = fmaxf(m_run, pmax);
      float corr = __expf(m_run - mn);
      l_run *= corr;
      m_run = mn;
      float cT[16];
      #pragma unroll
      for (int r = 0; r < 16; ++r)
        cT[r] = __shfl(corr, (r & 3) + 8 * (r >> 2) + hi2 * 4);
      #pragma unroll
      for (int dt = 0; dt < 4; ++dt)
        #pragma unroll
        for (int r = 0; r < 16; ++r) acc[dt][r] *= cT[r];
    }

    // P = exp(S - m_run); row-sum
    float p[16];
    #pragma unroll
    for (int r = 0; r < 16; ++r) p[r] = __expf(sv[r] - m_run);
    float s8[8];
    #pragma unroll
    for (int j = 0; j < 8; ++j) s8[j] = p[2 * j] + p[2 * j + 1];
    #pragma unroll
    for (int j = 0; j < 4; ++j) s8[j] = s8[j] + s8[j + 4];
    float rs = (s8[0] + s8[1]) + (s8[2] + s8[3]);
    rs += __shfl_xor(rs, 32);
    l_run += rs;

    // pack P; half-swap to build PV A-frags (R6/R8-verified)
    uint_t ow[8];
    #pragma unroll
    for (int j = 0; j < 8; ++j)
      ow[j] = (uint_t)f2bf(p[2 * j]) | ((uint_t)f2bf(p[2 * j + 1]) << 16);
    uint_t pw[8];
    #pragma unroll
    for (int j = 0; j < 8; ++j) pw[j] = __shfl_xor(ow[j], 32);
    u32x4 pa0 = (u32x4){hi2 ? pw[2] : ow[0], hi2 ? pw[3] : ow[1],
                        hi2 ? ow[2] : pw[0], hi2 ? ow[3] : pw[1]};
    u32x4 pa1 = (u32x4){hi2 ? pw[6] : ow[4], hi2 ? pw[7] : ow[5],
                        hi2 ? ow[6] : pw[4], hi2 ? ow[7] : pw[5]};
    bf16x8 paf0 = __builtin_bit_cast(bf16x8, pa0);
    bf16x8 paf1 = __builtin_bit_cast(bf16x8, pa1);

    // PV: paf0 ~ kv 0..15, paf1 ~ kv 16..31 of the chunk
    __builtin_amdgcn_s_setprio(1);
    #pragma unroll
    for (int dt = 0; dt < 4; ++dt) {
      int vd = dt * 32 + lo32;
      int c16a = hi2 ^ (vd & 3);
      int c16b = (2 + hi2) ^ (vd & 3);
      bf16x8 vfa = *(const bf16x8*)&vs[vd * 32 + c16a * 8];
      bf16x8 vfb = *(const bf16x8*)&vs[vd * 32 + c16b * 8];
      acc[dt] = __builtin_amdgcn_mfma_f32_32x32x16_bf16(paf0, vfa, acc[dt], 0, 0, 0);
      acc[dt] = __builtin_amdgcn_mfma_f32_32x32x16_bf16(paf1, vfb, acc[dt], 0, 0, 0);
    }
    __builtin_amdgcn_s_setprio(0);
    if (ch & 1) mw_cur = mw_nxt;
    __syncthreads();
  }

  // epilogue: write partials. (m,l) per q-row (hi2==0 lanes); N unnormalized bf16.
  if (hi2 == 0) {
    size_t row = (size_t)bh * L_ + qw + lo32;
    float2 v2 = make_float2(m_run, l_run);
    *(float2*)(ml + ((size_t)quar * BH_ * L_ + row) * 2) = v2;
  }
  ushort_t* np = (quar == 0) ? np0 : (quar == 1) ? np1 : (quar == 2) ? np2 : np3;
  #pragma unroll
  for (int dt = 0; dt < 4; ++dt)
    #pragma unroll
    for (int r = 0; r < 16; ++r) {
      int qrow = qw + (r & 3) + 8 * (r >> 2) + hi2 * 4;
      np[((size_t)bh * L_ + qrow) * D_ + dt * 32 + lo32] = f2bf(acc[dt][r]);
    }
}

// ------------------------------------------------- split-K combine (4-way)
__global__ __launch_bounds__(256)
void combine(const ushort_t* __restrict__ np0, const ushort_t* __restrict__ np1,
             const ushort_t* __restrict__ np2, const ushort_t* __restrict__ np3,
             const float* __restrict__ ml, ushort_t* __restrict__ obf) {
  int bh = blockIdx.x;
  int b = bh / H_, h = bh - b * H_;
  if (h == 0) return;                       // eye head written directly
  int t = threadIdx.x;
  int qi = t >> 4, di = t & 15;             // 16 q-rows x 16 d-groups of 8
  int qq = blockIdx.y * 16 + qi;
  size_t row = (size_t)bh * L_ + qq;
  float2 mlv[4];
  #pragma unroll
  for (int s = 0; s < 4; ++s)
    mlv[s] = *(const float2*)(ml + ((size_t)s * BH_ * L_ + row) * 2);
  float M = fmaxf(fmaxf(mlv[0].x, mlv[1].x), fmaxf(mlv[2].x, mlv[3].x));
  float w[4], lsum = 0.f;
  #pragma unroll
  for (int s = 0; s < 4; ++s) { w[s] = __expf(mlv[s].x - M); lsum += w[s] * mlv[s].y; }
  float inv = 1.f / lsum;
  bf16x8 n0 = *(const bf16x8*)(np0 + row * D_ + di * 8);
  bf16x8 n1 = *(const bf16x8*)(np1 + row * D_ + di * 8);
  bf16x8 n2 = *(const bf16x8*)(np2 + row * D_ + di * 8);
  bf16x8 n3 = *(const bf16x8*)(np3 + row * D_ + di * 8);
  ushort_t o[8];
  #pragma unroll
  for (int j = 0; j < 8; ++j)
    o[j] = f2bf((w[0] * bf2f((ushort_t)n0[j]) + w[1] * bf2f((ushort_t)n1[j]) +
                 w[2] * bf2f((ushort_t)n2[j]) + w[3] * bf2f((ushort_t)n3[j])) * inv);
  *(bf16x8*)(obf + ((size_t)b * L_ + qq) * C_ + h * D_ + di * 8) = *(bf16x8*)o;
}

// ---------------------------------------------------------------- launcher
extern "C" void kernel_launch(void* const* d_in, const int* in_sizes, int n_in,
                              void* d_out, int out_size, void* d_ws, size_t ws_size,
                              hipStream_t stream) {
  const float* x     = (const float*)d_in[0];
  const int*   adj   = (const int*)d_in[1];
  const int*   dist  = (const int*)d_in[2];
  const float* wqkv  = (const float*)d_in[3];
  const float* wproj = (const float*)d_in[4];
  float* out = (float*)d_out;
  char* ws = (char*)d_ws;

  const size_t SZ_X   = (size_t)B_ * L_ * C_ * 2;        // 12.6 MB (== SZ_QKV)
  const size_t SZ_WQ  = (size_t)3 * C_ * C_ * 2;
  const size_t SZ_WP  = (size_t)C_ * C_ * 2;
  const size_t SZ_QKV = (size_t)BH_ * L_ * D_ * 2;       // 12.6 MB
  const size_t SZ_MSK = (size_t)B_ * L_ * 16 * 8;        // 1 MB
  const size_t SZ_ML  = (size_t)4 * BH_ * L_ * 2 * 4;    // 1.6 MB
  size_t off = 0;
  ushort_t* xbf  = (ushort_t*)(ws + off); off += SZ_X;   // reused as np0 post-GEMM
  ushort_t* wqb  = (ushort_t*)(ws + off); off += SZ_WQ;
  ushort_t* wpb  = (ushort_t*)(ws + off); off += SZ_WP;
  ushort_t* qb   = (ushort_t*)(ws + off); off += SZ_QKV;
  ushort_t* kb   = (ushort_t*)(ws + off); off += SZ_QKV;
  ushort_t* vTb  = (ushort_t*)(ws + off); off += SZ_QKV;
  ushort_t* vb   = (ushort_t*)(ws + off); off += SZ_QKV;
  ushort_t* ob   = (ushort_t*)(ws + off); off += SZ_X;
  u64* a1p = (u64*)(ws + off); off += SZ_MSK;
  u64* a2p = (u64*)(ws + off); off += SZ_MSK;
  u64* d2p = (u64*)(ws + off); off += SZ_MSK;
  u64* d3p = (u64*)(ws + off); off += SZ_MSK;
  ushort_t* np1 = (ushort_t*)(ws + off); off += SZ_QKV;  // partial N quarter 1
  ushort_t* np2 = (ushort_t*)(ws + off); off += SZ_QKV;  // partial N quarter 2
  ushort_t* np3 = (ushort_t*)(ws + off); off += SZ_QKV;  // partial N quarter 3
  float*    mlb = (float*)(ws + off); off += SZ_ML;      // (m,l)[4][BH][L]
  ushort_t* np0 = xbf;                                   // partial N quarter 0
  (void)ws_size; (void)n_in; (void)in_sizes; (void)out_size;

  cvt_f32_bf16<<<(B_ * L_ * C_ / 8 + 255) / 256, 256, 0, stream>>>(x, xbf, B_ * L_ * C_ / 8);
  cvt_f32_bf16<<<(3 * C_ * C_ / 8 + 255) / 256, 256, 0, stream>>>(wqkv, wqb, 3 * C_ * C_ / 8);
  cvt_f32_bf16<<<(C_ * C_ / 8 + 255) / 256, 256, 0, stream>>>(wproj, wpb, C_ * C_ / 8);
  pack_masks<<<dim3(L_, B_), 256, 0, stream>>>(adj, dist, a1p, d2p, d3p);
  hop2<<<B_ * L_ / 64, 64, 0, stream>>>(a1p, a2p);
  // qkv = x @ wqkv^T  (M=8192, N=2304, K=768), nwg=1152 (%8==0)
  gemm_bt<0><<<dim3(3 * C_ / 128, B_ * L_ / 128), 256, 0, stream>>>(
      xbf, wqb, 3 * C_, C_, qb, kb, vTb, vb, nullptr);
  // attention split-K=4: 8-wave blocks, 256 q-rows; grid (bh, qt, quarter)
  attn_kernel<<<dim3(BH_, L_ / 256, 4), 512, 0, stream>>>(
      qb, kb, vTb, vb, ob, np0, np1, np2, np3, mlb, a1p, a2p, d2p, d3p);
  combine<<<dim3(BH_, L_ / 16), 256, 0, stream>>>(np0, np1, np2, np3, mlb, ob);
  // out = O @ wproj^T  (M=8192, N=768, K=768), nwg=384 (%8==0)
  gemm_bt<1><<<dim3(C_ / 128, B_ * L_ / 128), 256, 0, stream>>>(
      ob, wpb, C_, C_, nullptr, nullptr, nullptr, nullptr, out);
}